// Round 7
// baseline (1781.010 us; speedup 1.0000x reference)
//
#include <hip/hip_runtime.h>
#include <hip/hip_bf16.h>

typedef __hip_bfloat16 bf16;
typedef long long i64;
typedef unsigned short u16;
typedef __attribute__((ext_vector_type(8))) short bf16x8;   // MFMA A/B frag (8 bf16)
typedef __attribute__((ext_vector_type(4))) float f32x4;    // MFMA C/D frag

#define EPSV 1e-5f
#define WINLEN 2560
#define CHUNK 64

static __device__ __forceinline__ float ldf(const void* p, size_t i, int fb) {
  return fb ? __bfloat162float(((const bf16*)p)[i]) : ((const float*)p)[i];
}
static __device__ __forceinline__ u16 f2b(float f) {  // RNE f32->bf16 raw bits
  unsigned int u = __float_as_uint(f);
  u += 0x7FFF + ((u >> 16) & 1);
  return (u16)(u >> 16);
}
static __device__ __forceinline__ unsigned pk2(float a, float b) {  // 2x bf16 in one u32
  return (unsigned)f2b(a) | ((unsigned)f2b(b) << 16);
}
static __device__ __forceinline__ float lo2f(unsigned w) { return __uint_as_float(w << 16); }
static __device__ __forceinline__ float hi2f(unsigned w) { return __uint_as_float(w & 0xFFFF0000u); }

// ---------------- merged detectors + zero-init ----------------

__global__ void setup_kernel(const int* __restrict__ ei_w, const unsigned int* __restrict__ g,
                             int* __restrict__ eflag, int* __restrict__ fflag,
                             int* __restrict__ degcnt, int* __restrict__ fill,
                             int* __restrict__ wctr, int* __restrict__ pctr,
                             float* __restrict__ buf0, float* __restrict__ buf1,
                             float* __restrict__ ppacc, int n) {
  int i = blockIdx.x * 256 + threadIdx.x;
  if (i < n) { degcnt[i] = 0; fill[i] = 0; }
  if (blockIdx.x == 0) {
    __shared__ int nz;
    if (threadIdx.x == 0) { nz = 0; *pctr = 0; }
    if (threadIdx.x < 32) wctr[threadIdx.x] = 0;   // dynamic-chunk counters (6 layers x 4 slices)
    buf0[threadIdx.x] = 0.f; buf1[threadIdx.x] = 0.f;   // 256 each
    if (threadIdx.x < 128) ppacc[threadIdx.x] = 0.f;
    __syncthreads();
    for (int k = threadIdx.x; k < 1024; k += 256)
      if (ei_w[2 * k + 1] != 0) atomicAdd(&nz, 1);
    __syncthreads();
    if (threadIdx.x == 0) {
      *eflag = (nz == 0) ? 1 : 0;                 // 1 => int64
      *fflag = (g[0] == 0x3F803F80u) ? 1 : 0;     // 1 => bf16
    }
  }
}

// ---------------- merged independent preprocessing: inproj | deg | wfrag ----------------
// deg is now SINGLE-PASS (each edge read once; was 8x XCD-partitioned re-scan -> issue-bound).

__global__ void __launch_bounds__(256) pre_merged_kernel(
    const void* __restrict__ x, const void* __restrict__ W, const void* __restrict__ b,
    const void* __restrict__ ei, const void* __restrict__ convW,
    const int* __restrict__ eflag, const int* __restrict__ fflag,
    int* __restrict__ degcnt, u16* __restrict__ pre, float* __restrict__ acc0,
    u16* __restrict__ wf, int n, int in_dim, int e, int wtotal, int gi, int gf) {
  __shared__ float4 SS[256], QQ[256];
  int fb = *fflag;
  if ((int)blockIdx.x < gi) {
    // ---- input projection + BN partial stats ----
    int q = threadIdx.x & 31, g8 = threadIdx.x >> 5;
    int c = q * 4;
    float b0 = ldf(b, c, fb), b1 = ldf(b, c + 1, fb), b2v = ldf(b, c + 2, fb), b3 = ldf(b, c + 3, fb);
    float s0 = 0, s1 = 0, s2 = 0, s3 = 0, q0 = 0, q1 = 0, q2 = 0, q3 = 0;
    for (int node = blockIdx.x * 8 + g8; node < n; node += gi * 8) {
      float a0 = b0, a1 = b1, a2 = b2v, a3 = b3;
      for (int k = 0; k < in_dim; ++k) {
        float xv = ldf(x, (size_t)node * in_dim + k, fb);
        size_t w0 = (size_t)k * 128 + c;
        a0 = fmaf(xv, ldf(W, w0, fb), a0);
        a1 = fmaf(xv, ldf(W, w0 + 1, fb), a1);
        a2 = fmaf(xv, ldf(W, w0 + 2, fb), a2);
        a3 = fmaf(xv, ldf(W, w0 + 3, fb), a3);
      }
      unsigned w0p = pk2(a0, a1), w1p = pk2(a2, a3);
      *(uint2*)(pre + (size_t)node * 128 + c) = make_uint2(w0p, w1p);
      float r0 = lo2f(w0p), r1 = hi2f(w0p), r2 = lo2f(w1p), r3 = hi2f(w1p);
      s0 += r0; s1 += r1; s2 += r2; s3 += r3;
      q0 = fmaf(r0, r0, q0); q1 = fmaf(r1, r1, q1); q2 = fmaf(r2, r2, q2); q3 = fmaf(r3, r3, q3);
    }
    SS[threadIdx.x] = make_float4(s0, s1, s2, s3);
    QQ[threadIdx.x] = make_float4(q0, q1, q2, q3);
    __syncthreads();
    if (threadIdx.x < 32) {
      float4 a = SS[threadIdx.x], qq = QQ[threadIdx.x];
      for (int g2 = 1; g2 < 8; ++g2) {
        float4 u = SS[g2 * 32 + threadIdx.x], w = QQ[g2 * 32 + threadIdx.x];
        a.x += u.x; a.y += u.y; a.z += u.z; a.w += u.w;
        qq.x += w.x; qq.y += w.y; qq.z += w.z; qq.w += w.w;
      }
      int cc = threadIdx.x * 4;
      atomicAdd(&acc0[cc + 0], a.x); atomicAdd(&acc0[cc + 1], a.y);
      atomicAdd(&acc0[cc + 2], a.z); atomicAdd(&acc0[cc + 3], a.w);
      atomicAdd(&acc0[128 + cc + 0], qq.x); atomicAdd(&acc0[128 + cc + 1], qq.y);
      atomicAdd(&acc0[128 + cc + 2], qq.z); atomicAdd(&acc0[128 + cc + 3], qq.w);
    }
  } else if ((int)blockIdx.x < gi + gf) {
    // ---- degree count, single-pass (each edge once) ----
    int bid = blockIdx.x - gi;
    int stride = gf * 256;
    int fb64 = *eflag;
    for (int i = bid * 256 + threadIdx.x; i < e; i += stride) {
      int d;
      if (fb64) d = (int)((const i64*)ei)[(size_t)e + i];
      else      d = ((const int*)ei)[(size_t)e + i];
      atomicAdd(&degcnt[d], 1);
    }
  } else {
    // ---- conv_W -> global B-frag order (bf16) ----
    int bid = blockIdx.x - gi - gf;
    int i = bid * 256 + threadIdx.x;
    if (i < wtotal) {
      int l = i >> 14, r = i & 16383;
      int k = r >> 7, nn = r & 127;
      int s = k >> 5, quad = (k >> 3) & 3, j = k & 7;
      int ct = nn >> 4, n16 = nn & 15;
      wf[(size_t)l * 16384 + (ct * 4 + s) * 512 + quad * 128 + n16 * 8 + j] = f2b(ldf(convW, i, fb));
    }
  }
}

// ---- multi-block exclusive scan (dinv folded into A) ----

__global__ void __launch_bounds__(256) scanA_kernel(const int* __restrict__ deg,
                                                    int* __restrict__ rp,
                                                    int* __restrict__ bsum,
                                                    float* __restrict__ dinv, int n) {
  int base = blockIdx.x * 1024 + threadIdx.x * 4;
  int v0 = (base     < n) ? deg[base]     : 0;
  int v1 = (base + 1 < n) ? deg[base + 1] : 0;
  int v2 = (base + 2 < n) ? deg[base + 2] : 0;
  int v3 = (base + 3 < n) ? deg[base + 3] : 0;
  if (base     < n) dinv[base]     = rsqrtf((float)v0 + 1.0f);
  if (base + 1 < n) dinv[base + 1] = rsqrtf((float)v1 + 1.0f);
  if (base + 2 < n) dinv[base + 2] = rsqrtf((float)v2 + 1.0f);
  if (base + 3 < n) dinv[base + 3] = rsqrtf((float)v3 + 1.0f);
  int ts = v0 + v1 + v2 + v3;
  __shared__ int ls[256];
  ls[threadIdx.x] = ts;
  __syncthreads();
  for (int off = 1; off < 256; off <<= 1) {
    int u = (threadIdx.x >= off) ? ls[threadIdx.x - off] : 0;
    __syncthreads();
    ls[threadIdx.x] += u;
    __syncthreads();
  }
  int run = ls[threadIdx.x] - ts;
  if (base     < n) rp[base]     = run; run += v0;
  if (base + 1 < n) rp[base + 1] = run; run += v1;
  if (base + 2 < n) rp[base + 2] = run; run += v2;
  if (base + 3 < n) rp[base + 3] = run;
  if (threadIdx.x == 255) bsum[blockIdx.x] = ls[255];
}

__global__ void __launch_bounds__(256) scanB_kernel(int* __restrict__ bsum, int* __restrict__ rp,
                                                    int nb, int n, int e) {
  __shared__ int ls[256];
  int t = threadIdx.x;
  int v = (t < nb) ? bsum[t] : 0;
  ls[t] = v;
  __syncthreads();
  for (int off = 1; off < 256; off <<= 1) {
    int u = (t >= off) ? ls[t - off] : 0;
    __syncthreads();
    ls[t] += u;
    __syncthreads();
  }
  if (t < nb) bsum[t] = ls[t] - v;  // exclusive
  if (t == 0) rp[n] = e;
}

__global__ void scanC_kernel(int* __restrict__ rp, const int* __restrict__ bsum, int n) {
  int i = blockIdx.x * 256 + threadIdx.x;
  if (i < n) rp[i] += bsum[i >> 10];
}

// Single-pass fill (each edge once; cross-XCD csr byte-writes merge via byte-enable writeback).
__global__ void fill_kernel(const void* __restrict__ ei, const int* __restrict__ flag,
                            const int* __restrict__ row_ptr,
                            int* __restrict__ fill, int* __restrict__ csr_src, int e, int n) {
  int stride = gridDim.x * 256;
  int fb64 = *flag;
  for (int i = blockIdx.x * 256 + threadIdx.x; i < e; i += stride) {
    int d, s;
    if (fb64) {
      d = (int)((const i64*)ei)[(size_t)e + i];
      s = (int)((const i64*)ei)[i];
    } else {
      d = ((const int*)ei)[(size_t)e + i];
      s = ((const int*)ei)[i];
    }
    int pos = row_ptr[d] + atomicAdd(&fill[d], 1);
    csr_src[pos] = s;
  }
}

// ---------------- fused BN(from acc stats)+residual + MFMA GEMM, zeroes next acc ----------------

__global__ void __launch_bounds__(256) gemm_bn_kernel(
    const u16* __restrict__ pre, u16* __restrict__ hbuf,
    const float* __restrict__ accIn, float* __restrict__ accZ,
    const void* __restrict__ g, const void* __restrict__ beta, const int* __restrict__ fflag,
    const u16* __restrict__ wfL, const float* __restrict__ dinv,
    u16* __restrict__ u, int n, int use_res, float inv_n, int gOff) {
  __shared__ u16 At[4][2048];   // per-wave A tile in frag order: s*512 + lane*8
  __shared__ float SC[128], SH[128];
  int fb = *fflag;
  if (threadIdx.x < 128) {
    int c = threadIdx.x;
    float s = accIn[c], s2 = accIn[128 + c];
    float mean = s * inv_n;
    float var = s2 * inv_n - mean * mean;
    float sc = ldf(g, (size_t)gOff + c, fb) * rsqrtf(var + EPSV);
    SC[c] = sc;
    SH[c] = ldf(beta, (size_t)gOff + c, fb) - mean * sc;
  }
  if (blockIdx.x == 0) accZ[threadIdx.x] = 0.f;   // 256 floats for upcoming gather stats
  __syncthreads();

  int lane = threadIdx.x & 63;
  int wave = threadIdx.x >> 6;
  int n16 = lane & 15, quad = lane >> 4;
  u16* at = At[wave];
  int node = lane & 15;             // staging row
  int cgrp = lane >> 4;             // staging col group 0..3
  int ntiles = (n + 15) >> 4;
  for (int tile = blockIdx.x * 4 + wave; tile < ntiles; tile += gridDim.x * 4) {
    int n0 = tile * 16;
    int gn = n0 + node;
    // ---- stage hnew tile (frag order), 8 channels (16B) per iter ----
#pragma unroll
    for (int r = 0; r < 4; ++r) {
      int c8 = r * 4 + cgrp;        // 0..15
      int c = c8 * 8;
      uint4 ww = make_uint4(0u, 0u, 0u, 0u);
      if (gn < n) {
        uint4 pv = *(const uint4*)(pre + (size_t)gn * 128 + c);
        unsigned pw[4] = {pv.x, pv.y, pv.z, pv.w};
        float h[8];
#pragma unroll
        for (int m = 0; m < 4; ++m) {
          h[2 * m]     = fmaxf(fmaf(lo2f(pw[m]), SC[c + 2 * m],     SH[c + 2 * m]), 0.f);
          h[2 * m + 1] = fmaxf(fmaf(hi2f(pw[m]), SC[c + 2 * m + 1], SH[c + 2 * m + 1]), 0.f);
        }
        if (use_res) {
          uint4 rv = *(const uint4*)(hbuf + (size_t)gn * 128 + c);
          unsigned rw[4] = {rv.x, rv.y, rv.z, rv.w};
#pragma unroll
          for (int m = 0; m < 4; ++m) {
            h[2 * m] += lo2f(rw[m]); h[2 * m + 1] += hi2f(rw[m]);
          }
        }
        ww.x = pk2(h[0], h[1]); ww.y = pk2(h[2], h[3]);
        ww.z = pk2(h[4], h[5]); ww.w = pk2(h[6], h[7]);
        *(uint4*)(hbuf + (size_t)gn * 128 + c) = ww;
      }
      int c4 = c8 * 2;              // even
      int s = c4 >> 3, qd = (c4 >> 1) & 3;
      *(uint4*)(at + s * 512 + qd * 128 + node * 8) = ww;   // 8 u16 = j 0..7
    }
    __builtin_amdgcn_s_waitcnt(0);  // drain LDS writes (wave-local tile)
    // ---- MFMA: 4 K-steps x 8 col-tiles; B from global wf ----
    f32x4 acc[8];
#pragma unroll
    for (int ct = 0; ct < 8; ++ct) acc[ct] = (f32x4){0.f, 0.f, 0.f, 0.f};
#pragma unroll
    for (int s = 0; s < 4; ++s) {
      bf16x8 af = *(const bf16x8*)(at + s * 512 + lane * 8);
#pragma unroll
      for (int ct = 0; ct < 8; ++ct) {
        bf16x8 bfr = *(const bf16x8*)(wfL + (size_t)(ct * 4 + s) * 512 + lane * 8);
        acc[ct] = __builtin_amdgcn_mfma_f32_16x16x32_bf16(af, bfr, acc[ct], 0, 0, 0);
      }
    }
    // ---- store D scaled by dinv[row], 4-slice-major ----
    float dv[4];
#pragma unroll
    for (int r = 0; r < 4; ++r) {
      int row = n0 + quad * 4 + r;
      dv[r] = (row < n) ? dinv[row] : 0.f;
    }
#pragma unroll
    for (int ct = 0; ct < 8; ++ct) {
#pragma unroll
      for (int r = 0; r < 4; ++r) {
        int row = n0 + quad * 4 + r;
        if (row < n)
          u[((size_t)(ct >> 1) * n + row) * 32 + (ct & 1) * 16 + n16] = f2b(acc[ct][r] * dv[r]);
      }
    }
  }
}

// ---------------- fused gather, 4-slice, dynamic chunks; stats atomicAdd into accOut ----------------

__global__ void __launch_bounds__(256) gather_stats_kernel(
    const int* __restrict__ row_ptr, const int* __restrict__ csr_src,
    const u16* __restrict__ u, const float* __restrict__ dinv,
    const void* __restrict__ b, const int* __restrict__ fflag,
    u16* __restrict__ pre, float* __restrict__ accOut,
    int* __restrict__ wctr, int n, int nch, size_t bOff) {
  __shared__ int sm[WINLEN];
  __shared__ float SW[4][4][8], QW[4][4][8];
  __shared__ int curchunk;
  int fb = *fflag;
  int ct2 = blockIdx.x & 3;
  const u16* us = u + (size_t)ct2 * n * 32;
  int q = threadIdx.x & 3;           // 16B quarter of the 64B node-slice
  int g = threadIdx.x >> 2;          // node group 0..63
  int c = ct2 * 32 + q * 8;          // global channel base
  float bias[8];
#pragma unroll
  for (int i = 0; i < 8; ++i) bias[i] = ldf(b, bOff + c + i, fb);
  float sA[8], qA[8];
#pragma unroll
  for (int i = 0; i < 8; ++i) { sA[i] = 0.f; qA[i] = 0.f; }

  for (;;) {
    __syncthreads();   // prior chunk fully consumed (sm + curchunk)
    if (threadIdx.x == 0) curchunk = atomicAdd(&wctr[ct2], 1);
    __syncthreads();
    int ch = curchunk;
    if (ch >= nch) break;
    int c0 = ch * CHUNK;
    int node = c0 + g;
    int valid = node < n;
    int beg = valid ? row_ptr[node] : 0;
    int end = valid ? row_ptr[node + 1] : 0;
    int cend = c0 + CHUNK; if (cend > n) cend = n;
    int chunk_lo = row_ptr[c0];
    int chunk_hi = row_ptr[cend];
    float acc[8];
    if (valid) {
      uint4 su = *(const uint4*)(us + (size_t)node * 32 + q * 8);
      acc[0] = lo2f(su.x); acc[1] = hi2f(su.x);
      acc[2] = lo2f(su.y); acc[3] = hi2f(su.y);
      acc[4] = lo2f(su.z); acc[5] = hi2f(su.z);
      acc[6] = lo2f(su.w); acc[7] = hi2f(su.w);
    } else {
#pragma unroll
      for (int i = 0; i < 8; ++i) acc[i] = 0.f;
    }
    for (int wlo = chunk_lo; wlo < chunk_hi; wlo += WINLEN) {
      int wlen = chunk_hi - wlo; if (wlen > WINLEN) wlen = WINLEN;
      __syncthreads();   // previous window fully consumed
      for (int i = threadIdx.x; i < wlen; i += 256)
        sm[i] = __builtin_nontemporal_load(csr_src + wlo + i);
      __syncthreads();
      int j0 = beg > wlo ? beg : wlo;
      int j1 = end < wlo + wlen ? end : wlo + wlen;
      int j = j0;
#define ACC(UU) \
      acc[0] += lo2f(UU.x); acc[1] += hi2f(UU.x); \
      acc[2] += lo2f(UU.y); acc[3] += hi2f(UU.y); \
      acc[4] += lo2f(UU.z); acc[5] += hi2f(UU.z); \
      acc[6] += lo2f(UU.w); acc[7] += hi2f(UU.w);
      for (; j + 8 <= j1; j += 8) {
        int i0 = sm[j - wlo],     i1 = sm[j - wlo + 1], i2 = sm[j - wlo + 2], i3 = sm[j - wlo + 3];
        int i4 = sm[j - wlo + 4], i5 = sm[j - wlo + 5], i6 = sm[j - wlo + 6], i7 = sm[j - wlo + 7];
        uint4 U0 = *(const uint4*)(us + (size_t)i0 * 32 + q * 8);
        uint4 U1 = *(const uint4*)(us + (size_t)i1 * 32 + q * 8);
        uint4 U2 = *(const uint4*)(us + (size_t)i2 * 32 + q * 8);
        uint4 U3 = *(const uint4*)(us + (size_t)i3 * 32 + q * 8);
        uint4 U4 = *(const uint4*)(us + (size_t)i4 * 32 + q * 8);
        uint4 U5 = *(const uint4*)(us + (size_t)i5 * 32 + q * 8);
        uint4 U6 = *(const uint4*)(us + (size_t)i6 * 32 + q * 8);
        uint4 U7 = *(const uint4*)(us + (size_t)i7 * 32 + q * 8);
        ACC(U0) ACC(U1) ACC(U2) ACC(U3) ACC(U4) ACC(U5) ACC(U6) ACC(U7)
      }
      for (; j + 4 <= j1; j += 4) {
        int i0 = sm[j - wlo], i1 = sm[j - wlo + 1], i2 = sm[j - wlo + 2], i3 = sm[j - wlo + 3];
        uint4 U0 = *(const uint4*)(us + (size_t)i0 * 32 + q * 8);
        uint4 U1 = *(const uint4*)(us + (size_t)i1 * 32 + q * 8);
        uint4 U2 = *(const uint4*)(us + (size_t)i2 * 32 + q * 8);
        uint4 U3 = *(const uint4*)(us + (size_t)i3 * 32 + q * 8);
        ACC(U0) ACC(U1) ACC(U2) ACC(U3)
      }
      for (; j < j1; ++j) {
        int i0 = sm[j - wlo];
        uint4 U0 = *(const uint4*)(us + (size_t)i0 * 32 + q * 8);
        ACC(U0)
      }
#undef ACC
    }
    if (valid) {
      float dv = dinv[node];
      float o0 = fmaf(acc[0], dv, bias[0]), o1 = fmaf(acc[1], dv, bias[1]);
      float o2 = fmaf(acc[2], dv, bias[2]), o3 = fmaf(acc[3], dv, bias[3]);
      float o4 = fmaf(acc[4], dv, bias[4]), o5 = fmaf(acc[5], dv, bias[5]);
      float o6 = fmaf(acc[6], dv, bias[6]), o7 = fmaf(acc[7], dv, bias[7]);
      unsigned w0 = pk2(o0, o1), w1 = pk2(o2, o3), w2 = pk2(o4, o5), w3 = pk2(o6, o7);
      *(uint4*)(pre + (size_t)node * 128 + c) = make_uint4(w0, w1, w2, w3);
      float r0 = lo2f(w0), r1 = hi2f(w0), r2 = lo2f(w1), r3 = hi2f(w1);
      float r4 = lo2f(w2), r5 = hi2f(w2), r6 = lo2f(w3), r7 = hi2f(w3);
      sA[0] += r0; sA[1] += r1; sA[2] += r2; sA[3] += r3;
      sA[4] += r4; sA[5] += r5; sA[6] += r6; sA[7] += r7;
      qA[0] = fmaf(r0, r0, qA[0]); qA[1] = fmaf(r1, r1, qA[1]);
      qA[2] = fmaf(r2, r2, qA[2]); qA[3] = fmaf(r3, r3, qA[3]);
      qA[4] = fmaf(r4, r4, qA[4]); qA[5] = fmaf(r5, r5, qA[5]);
      qA[6] = fmaf(r6, r6, qA[6]); qA[7] = fmaf(r7, r7, qA[7]);
    }
  }
  // wave butterfly over node-groups (keep q=tid&3 invariant: xor masks multiples of 4)
#pragma unroll
  for (int m = 4; m <= 32; m <<= 1) {
#pragma unroll
    for (int i = 0; i < 8; ++i) {
      sA[i] += __shfl_xor(sA[i], m, 64);
      qA[i] += __shfl_xor(qA[i], m, 64);
    }
  }
  int lane = threadIdx.x & 63, wv = threadIdx.x >> 6;
  if (lane < 4) {
#pragma unroll
    for (int i = 0; i < 8; ++i) { SW[wv][lane][i] = sA[i]; QW[wv][lane][i] = qA[i]; }
  }
  __syncthreads();
  if (threadIdx.x < 32) {
    int qq = threadIdx.x >> 3, i = threadIdx.x & 7;
    float a = SW[0][qq][i] + SW[1][qq][i] + SW[2][qq][i] + SW[3][qq][i];
    float b2 = QW[0][qq][i] + QW[1][qq][i] + QW[2][qq][i] + QW[3][qq][i];
    int chn = ct2 * 32 + qq * 8 + i;
    atomicAdd(&accOut[chn], a);
    atomicAdd(&accOut[128 + chn], b2);
  }
}

// ---------------- fused final: BN-apply + residual + policy MLP + pool + value (last block) ----

__global__ void __launch_bounds__(256) policy_pool_kernel(
    const u16* __restrict__ pre, const u16* __restrict__ hbuf,
    const float* __restrict__ accIn,
    const void* __restrict__ bg, const void* __restrict__ bbeta, int gOff,
    const void* __restrict__ pW1, const void* __restrict__ pb1,
    const void* __restrict__ pW2, const void* __restrict__ pb2,
    const void* __restrict__ vW1, const void* __restrict__ vb1,
    const void* __restrict__ vW2, const void* __restrict__ vb2,
    const int* __restrict__ fflag, float* __restrict__ ppacc, int* __restrict__ pctr,
    void* __restrict__ out, int n, float inv_n) {
  __shared__ float W1[128 * 32];
  __shared__ float B1v[32], W2v[32];
  __shared__ float SC[128], SH[128];
  __shared__ int plast;
  int fb = *fflag;
  for (int i = threadIdx.x; i < 128 * 32; i += 256) W1[i] = ldf(pW1, i, fb);
  if (threadIdx.x < 32) {
    B1v[threadIdx.x] = ldf(pb1, threadIdx.x, fb);
    W2v[threadIdx.x] = ldf(pW2, threadIdx.x, fb);
  }
  if (threadIdx.x < 128) {
    int cch = threadIdx.x;
    float s = accIn[cch], s2 = accIn[128 + cch];
    float mean = s * inv_n;
    float var = s2 * inv_n - mean * mean;
    float sc = ldf(bg, (size_t)gOff + cch, fb) * rsqrtf(var + EPSV);
    SC[cch] = sc;
    SH[cch] = ldf(bbeta, (size_t)gOff + cch, fb) - mean * sc;
  }
  __syncthreads();
  float bias2 = ldf(pb2, 0, fb);
  int q = threadIdx.x & 31, g8 = threadIdx.x >> 5;
  int c = q * 4;
  float4 sc = *(const float4*)&SC[c];
  float4 sh = *(const float4*)&SH[c];
  float cs0 = 0, cs1 = 0, cs2 = 0, cs3 = 0;
  for (int node = blockIdx.x * 8 + g8; node < n; node += gridDim.x * 8) {
    uint2 pv = *(const uint2*)(pre + (size_t)node * 128 + c);
    uint2 rv = *(const uint2*)(hbuf + (size_t)node * 128 + c);
    float4 h4;
    h4.x = fmaxf(fmaf(lo2f(pv.x), sc.x, sh.x), 0.f) + lo2f(rv.x);
    h4.y = fmaxf(fmaf(hi2f(pv.x), sc.y, sh.y), 0.f) + hi2f(rv.x);
    h4.z = fmaxf(fmaf(lo2f(pv.y), sc.z, sh.z), 0.f) + lo2f(rv.y);
    h4.w = fmaxf(fmaf(hi2f(pv.y), sc.w, sh.w), 0.f) + hi2f(rv.y);
    cs0 += h4.x; cs1 += h4.y; cs2 += h4.z; cs3 += h4.w;
    float acc = B1v[q];
#pragma unroll
    for (int k4 = 0; k4 < 32; ++k4) {
      float hx = __shfl(h4.x, k4, 32);
      float hy = __shfl(h4.y, k4, 32);
      float hz = __shfl(h4.z, k4, 32);
      float hw = __shfl(h4.w, k4, 32);
      int k = k4 * 4;
      acc = fmaf(hx, W1[k * 32 + q], acc);
      acc = fmaf(hy, W1[(k + 1) * 32 + q], acc);
      acc = fmaf(hz, W1[(k + 2) * 32 + q], acc);
      acc = fmaf(hw, W1[(k + 3) * 32 + q], acc);
    }
    acc = fmaxf(acc, 0.f) * W2v[q];
    for (int off = 16; off; off >>= 1) acc += __shfl_down(acc, off, 32);
    if (q == 0) {
      float v = acc + bias2;
      if (fb) ((bf16*)out)[node] = __float2bfloat16(v);
      else    ((float*)out)[node] = v;
    }
  }
  __shared__ float4 SS[256];
  SS[threadIdx.x] = make_float4(cs0, cs1, cs2, cs3);
  __syncthreads();
  if (threadIdx.x < 32) {
    float4 a = SS[threadIdx.x];
    for (int g2 = 1; g2 < 8; ++g2) {
      float4 u = SS[g2 * 32 + threadIdx.x];
      a.x += u.x; a.y += u.y; a.z += u.z; a.w += u.w;
    }
    int cc = threadIdx.x * 4;
    atomicAdd(&ppacc[cc + 0], a.x); atomicAdd(&ppacc[cc + 1], a.y);
    atomicAdd(&ppacc[cc + 2], a.z); atomicAdd(&ppacc[cc + 3], a.w);
  }
  __syncthreads();   // all this block's ppacc adds performed before counter bump
  if (threadIdx.x == 0) {
    int old = atomicAdd(pctr, 1);
    plast = (old == (int)gridDim.x - 1) ? 1 : 0;
  }
  __syncthreads();
  if (plast) {
    __shared__ float gs[128];
    if (threadIdx.x < 128) gs[threadIdx.x] = atomicAdd(&ppacc[threadIdx.x], 0.f);  // coherent read
    __syncthreads();
    if (threadIdx.x < 64) {
      int cc = threadIdx.x;
      float acc2 = ldf(vb1, cc, fb);
      for (int k = 0; k < 128; ++k)
        acc2 = fmaf(gs[k] * inv_n, ldf(vW1, (size_t)k * 64 + cc, fb), acc2);
      acc2 = fmaxf(acc2, 0.f);
      float v = acc2 * ldf(vW2, cc, fb);
      for (int off = 32; off; off >>= 1) v += __shfl_down(v, off, 64);
      if (cc == 0) {
        float rr = tanhf(v + ldf(vb2, 0, fb));
        if (fb) ((bf16*)out)[n] = __float2bfloat16(rr);
        else    ((float*)out)[n] = rr;
      }
    }
  }
}

// ---------------- host ----------------

extern "C" void kernel_launch(void* const* d_in, const int* in_sizes, int n_in,
                              void* d_out, int out_size, void* d_ws, size_t ws_size,
                              hipStream_t stream) {
  const void* x       = d_in[0];
  const void* ei      = d_in[1];
  const void* in_W    = d_in[3];
  const void* in_b    = d_in[4];
  const void* in_g    = d_in[5];
  const void* in_beta = d_in[6];
  const void* conv_W  = d_in[7];
  const void* conv_b  = d_in[8];
  const void* bn_g    = d_in[9];
  const void* bn_beta = d_in[10];
  const void* pW1     = d_in[11];
  const void* pb1     = d_in[12];
  const void* pW2     = d_in[13];
  const void* pb2     = d_in[14];
  const void* vW1     = d_in[15];
  const void* vb1     = d_in[16];
  const void* vW2     = d_in[17];
  const void* vb2     = d_in[18];

  const int H = 128;
  int in_dim = in_sizes[3] / H;        // 5
  int n      = in_sizes[0] / in_dim;   // 100000
  int e      = in_sizes[1] / 2;        // 3200000
  int L      = in_sizes[7] / (H * H);  // 6

  const int GS  = 2048;  // gather grid (multiple of 4)
  const int GI  = 512;   // inproj grid
  const int GP  = 1024;  // policy grid
  const int GF  = 2048;  // deg/fill grid

  char* w = (char*)d_ws;
  u16*   u    = (u16*)w;   w += (size_t)n * H * sizeof(u16);
  u16*   pre  = (u16*)w;   w += (size_t)n * H * sizeof(u16);
  u16*   hbuf = (u16*)w;   w += (size_t)n * H * sizeof(u16);
  int*   csr_src  = (int*)w;   w += ((size_t)e + 16) * sizeof(int);
  int*   row_ptr  = (int*)w;   w += (size_t)(n + 1 + 15) / 16 * 16 * sizeof(int);
  int*   degcnt   = (int*)w;   w += (size_t)n * sizeof(int);
  int*   fillc    = (int*)w;   w += (size_t)n * sizeof(int);
  float* dinv     = (float*)w; w += (size_t)n * sizeof(float);
  int*   eflag = (int*)w;   w += 16 * sizeof(int);
  int*   fflag = (int*)w;   w += 16 * sizeof(int);
  int*   bsum  = (int*)w;   w += 256 * sizeof(int);
  int*   wctr  = (int*)w;   w += 32 * sizeof(int);   // 6 layers x 4 slices dynamic counters
  int*   pctr  = (int*)w;   w += 16 * sizeof(int);
  float* buf0  = (float*)w; w += 256 * sizeof(float);
  float* buf1  = (float*)w; w += 256 * sizeof(float);
  float* ppacc = (float*)w; w += 128 * sizeof(float);
  u16*   wf    = (u16*)w;   w += (size_t)L * H * H * sizeof(u16);

  int gN = (n + 255) / 256;
  int nb = (n + 1023) >> 10;
  int nch = (n + CHUNK - 1) / CHUNK;
  int wtotal = L * H * H;
  int GW = (wtotal + 255) / 256;
  float inv_n = 1.0f / (float)n;
  float* bufs[2] = {buf0, buf1};

  setup_kernel<<<gN, 256, 0, stream>>>((const int*)ei, (const unsigned int*)in_g,
                                       eflag, fflag, degcnt, fillc, wctr, pctr,
                                       buf0, buf1, ppacc, n);
  pre_merged_kernel<<<GI + GF + GW, 256, 0, stream>>>(
      x, in_W, in_b, ei, conv_W, eflag, fflag, degcnt, pre, buf0, wf,
      n, in_dim, e, wtotal, GI, GF);
  scanA_kernel<<<nb, 256, 0, stream>>>(degcnt, row_ptr, bsum, dinv, n);
  scanB_kernel<<<1, 256, 0, stream>>>(bsum, row_ptr, nb, n, e);
  scanC_kernel<<<gN, 256, 0, stream>>>(row_ptr, bsum, n);
  fill_kernel<<<GF, 256, 0, stream>>>(ei, eflag, row_ptr, fillc, csr_src, e, n);

  for (int l = 0; l < L; ++l) {
    const void* g    = (l == 0) ? in_g    : bn_g;
    const void* beta = (l == 0) ? in_beta : bn_beta;
    int gOff = (l == 0) ? 0 : (l - 1) * H;
    gemm_bn_kernel<<<2048, 256, 0, stream>>>(pre, hbuf, bufs[l & 1], bufs[(l + 1) & 1],
                                             g, beta, fflag, wf + (size_t)l * H * H,
                                             dinv, u, n, (l > 0) ? 1 : 0, inv_n, gOff);
    gather_stats_kernel<<<GS, 256, 0, stream>>>(row_ptr, csr_src, u, dinv,
                                                conv_b, fflag, pre, bufs[(l + 1) & 1],
                                                wctr + l * 4, n, nch, (size_t)l * H);
  }

  policy_pool_kernel<<<GP, 256, 0, stream>>>(pre, hbuf, bufs[L & 1],
                                             bn_g, bn_beta, (L - 1) * H,
                                             pW1, pb1, pW2, pb2, vW1, vb1, vW2, vb2,
                                             fflag, ppacc, pctr, d_out, n, inv_n);
}

// Round 8
// 1677.442 us; speedup vs baseline: 1.0617x; 1.0617x over previous
//
#include <hip/hip_runtime.h>
#include <hip/hip_bf16.h>

typedef __hip_bfloat16 bf16;
typedef long long i64;
typedef unsigned short u16;
typedef __attribute__((ext_vector_type(8))) short bf16x8;   // MFMA A/B frag (8 bf16)
typedef __attribute__((ext_vector_type(4))) float f32x4;    // MFMA C/D frag
typedef __attribute__((ext_vector_type(2))) long long ll2;  // 2x int64 edge load

#define EPSV 1e-5f
#define WINLEN 2560
#define CHUNK 64

static __device__ __forceinline__ float ldf(const void* p, size_t i, int fb) {
  return fb ? __bfloat162float(((const bf16*)p)[i]) : ((const float*)p)[i];
}
static __device__ __forceinline__ u16 f2b(float f) {  // RNE f32->bf16 raw bits
  unsigned int u = __float_as_uint(f);
  u += 0x7FFF + ((u >> 16) & 1);
  return (u16)(u >> 16);
}
static __device__ __forceinline__ unsigned pk2(float a, float b) {  // 2x bf16 in one u32
  return (unsigned)f2b(a) | ((unsigned)f2b(b) << 16);
}
static __device__ __forceinline__ float lo2f(unsigned w) { return __uint_as_float(w << 16); }
static __device__ __forceinline__ float hi2f(unsigned w) { return __uint_as_float(w & 0xFFFF0000u); }

// ---------------- merged detectors + zero-init ----------------

__global__ void setup_kernel(const int* __restrict__ ei_w, const unsigned int* __restrict__ g,
                             int* __restrict__ eflag, int* __restrict__ fflag,
                             int* __restrict__ degcnt,
                             int* __restrict__ wctr, int* __restrict__ pctr,
                             float* __restrict__ buf0, float* __restrict__ buf1,
                             float* __restrict__ ppacc, int n) {
  int i = blockIdx.x * 256 + threadIdx.x;
  if (i < n) degcnt[i] = 0;
  if (blockIdx.x == 0) {
    __shared__ int nz;
    if (threadIdx.x == 0) { nz = 0; *pctr = 0; }
    if (threadIdx.x < 32) wctr[threadIdx.x] = 0;   // dynamic-chunk counters (6 layers x 4 slices)
    buf0[threadIdx.x] = 0.f; buf1[threadIdx.x] = 0.f;   // 256 each
    if (threadIdx.x < 128) ppacc[threadIdx.x] = 0.f;
    __syncthreads();
    for (int k = threadIdx.x; k < 1024; k += 256)
      if (ei_w[2 * k + 1] != 0) atomicAdd(&nz, 1);
    __syncthreads();
    if (threadIdx.x == 0) {
      *eflag = (nz == 0) ? 1 : 0;                 // 1 => int64
      *fflag = (g[0] == 0x3F803F80u) ? 1 : 0;     // 1 => bf16
    }
  }
}

// ---------------- merged independent preprocessing: inproj | deg | wfrag ----------------
// deg reverted to scalar XCD dst-partitioned 8-slice (measured-best: L3 absorbs the 8x
// re-reads; slice-per-XCD keeps degcnt atomics L2-local. Single-pass cross-XCD atomics
// measured WORSE — R7; 4-wide vectorization measured WORSE — R6).

__global__ void __launch_bounds__(256) pre_merged_kernel(
    const void* __restrict__ x, const void* __restrict__ W, const void* __restrict__ b,
    const void* __restrict__ ei, const void* __restrict__ convW,
    const int* __restrict__ eflag, const int* __restrict__ fflag,
    int* __restrict__ degcnt, u16* __restrict__ pre, float* __restrict__ acc0,
    u16* __restrict__ wf, int n, int in_dim, int e, int wtotal, int gi, int gf) {
  __shared__ float4 SS[256], QQ[256];
  int fb = *fflag;
  if ((int)blockIdx.x < gi) {
    // ---- input projection + BN partial stats ----
    int q = threadIdx.x & 31, g8 = threadIdx.x >> 5;
    int c = q * 4;
    float b0 = ldf(b, c, fb), b1 = ldf(b, c + 1, fb), b2v = ldf(b, c + 2, fb), b3 = ldf(b, c + 3, fb);
    float s0 = 0, s1 = 0, s2 = 0, s3 = 0, q0 = 0, q1 = 0, q2 = 0, q3 = 0;
    for (int node = blockIdx.x * 8 + g8; node < n; node += gi * 8) {
      float a0 = b0, a1 = b1, a2 = b2v, a3 = b3;
      for (int k = 0; k < in_dim; ++k) {
        float xv = ldf(x, (size_t)node * in_dim + k, fb);
        size_t w0 = (size_t)k * 128 + c;
        a0 = fmaf(xv, ldf(W, w0, fb), a0);
        a1 = fmaf(xv, ldf(W, w0 + 1, fb), a1);
        a2 = fmaf(xv, ldf(W, w0 + 2, fb), a2);
        a3 = fmaf(xv, ldf(W, w0 + 3, fb), a3);
      }
      unsigned w0p = pk2(a0, a1), w1p = pk2(a2, a3);
      *(uint2*)(pre + (size_t)node * 128 + c) = make_uint2(w0p, w1p);
      float r0 = lo2f(w0p), r1 = hi2f(w0p), r2 = lo2f(w1p), r3 = hi2f(w1p);
      s0 += r0; s1 += r1; s2 += r2; s3 += r3;
      q0 = fmaf(r0, r0, q0); q1 = fmaf(r1, r1, q1); q2 = fmaf(r2, r2, q2); q3 = fmaf(r3, r3, q3);
    }
    SS[threadIdx.x] = make_float4(s0, s1, s2, s3);
    QQ[threadIdx.x] = make_float4(q0, q1, q2, q3);
    __syncthreads();
    if (threadIdx.x < 32) {
      float4 a = SS[threadIdx.x], qq = QQ[threadIdx.x];
      for (int g2 = 1; g2 < 8; ++g2) {
        float4 u = SS[g2 * 32 + threadIdx.x], w = QQ[g2 * 32 + threadIdx.x];
        a.x += u.x; a.y += u.y; a.z += u.z; a.w += u.w;
        qq.x += w.x; qq.y += w.y; qq.z += w.z; qq.w += w.w;
      }
      int cc = threadIdx.x * 4;
      atomicAdd(&acc0[cc + 0], a.x); atomicAdd(&acc0[cc + 1], a.y);
      atomicAdd(&acc0[cc + 2], a.z); atomicAdd(&acc0[cc + 3], a.w);
      atomicAdd(&acc0[128 + cc + 0], qq.x); atomicAdd(&acc0[128 + cc + 1], qq.y);
      atomicAdd(&acc0[128 + cc + 2], qq.z); atomicAdd(&acc0[128 + cc + 3], qq.w);
    }
  } else if ((int)blockIdx.x < gi + gf) {
    // ---- degree count, XCD dst-partitioned, scalar ----
    int bid = blockIdx.x - gi;
    int k = bid & 7;
    int lo = (int)(((long long)n * k) >> 3);
    int hi = (int)(((long long)n * (k + 1)) >> 3);
    int stride = (gf >> 3) * 256;
    int fb64 = *eflag;
    for (int i = (bid >> 3) * 256 + threadIdx.x; i < e; i += stride) {
      int d;
      if (fb64) d = (int)((const i64*)ei)[(size_t)e + i];
      else      d = ((const int*)ei)[(size_t)e + i];
      if (d >= lo && d < hi) atomicAdd(&degcnt[d], 1);
    }
  } else {
    // ---- conv_W -> global B-frag order (bf16) ----
    int bid = blockIdx.x - gi - gf;
    int i = bid * 256 + threadIdx.x;
    if (i < wtotal) {
      int l = i >> 14, r = i & 16383;
      int k = r >> 7, nn = r & 127;
      int s = k >> 5, quad = (k >> 3) & 3, j = k & 7;
      int ct = nn >> 4, n16 = nn & 15;
      wf[(size_t)l * 16384 + (ct * 4 + s) * 512 + quad * 128 + n16 * 8 + j] = f2b(ldf(convW, i, fb));
    }
  }
}

// ---- multi-block exclusive scan (dinv folded into A) ----

__global__ void __launch_bounds__(256) scanA_kernel(const int* __restrict__ deg,
                                                    int* __restrict__ rp,
                                                    int* __restrict__ bsum,
                                                    float* __restrict__ dinv, int n) {
  int base = blockIdx.x * 1024 + threadIdx.x * 4;
  int v0 = (base     < n) ? deg[base]     : 0;
  int v1 = (base + 1 < n) ? deg[base + 1] : 0;
  int v2 = (base + 2 < n) ? deg[base + 2] : 0;
  int v3 = (base + 3 < n) ? deg[base + 3] : 0;
  if (base     < n) dinv[base]     = rsqrtf((float)v0 + 1.0f);
  if (base + 1 < n) dinv[base + 1] = rsqrtf((float)v1 + 1.0f);
  if (base + 2 < n) dinv[base + 2] = rsqrtf((float)v2 + 1.0f);
  if (base + 3 < n) dinv[base + 3] = rsqrtf((float)v3 + 1.0f);
  int ts = v0 + v1 + v2 + v3;
  __shared__ int ls[256];
  ls[threadIdx.x] = ts;
  __syncthreads();
  for (int off = 1; off < 256; off <<= 1) {
    int u = (threadIdx.x >= off) ? ls[threadIdx.x - off] : 0;
    __syncthreads();
    ls[threadIdx.x] += u;
    __syncthreads();
  }
  int run = ls[threadIdx.x] - ts;
  if (base     < n) rp[base]     = run; run += v0;
  if (base + 1 < n) rp[base + 1] = run; run += v1;
  if (base + 2 < n) rp[base + 2] = run; run += v2;
  if (base + 3 < n) rp[base + 3] = run;
  if (threadIdx.x == 255) bsum[blockIdx.x] = ls[255];
}

__global__ void __launch_bounds__(256) scanB_kernel(int* __restrict__ bsum, int* __restrict__ rp,
                                                    int nb, int n, int e) {
  __shared__ int ls[256];
  int t = threadIdx.x;
  int v = (t < nb) ? bsum[t] : 0;
  ls[t] = v;
  __syncthreads();
  for (int off = 1; off < 256; off <<= 1) {
    int u = (t >= off) ? ls[t - off] : 0;
    __syncthreads();
    ls[t] += u;
    __syncthreads();
  }
  if (t < nb) bsum[t] = ls[t] - v;  // exclusive
  if (t == 0) rp[n] = e;
}

// fixup + write rpw copy (fill's direct-allocation counters; saves the row_ptr load in fill).
__global__ void scanC_kernel(int* __restrict__ rp, const int* __restrict__ bsum,
                             int* __restrict__ rpw, int n) {
  int i = blockIdx.x * 256 + threadIdx.x;
  if (i < n) {
    int v = rp[i] + bsum[i >> 10];
    rp[i] = v;
    rpw[i] = v;
  }
}

// XCD dst-partitioned fill, 4 edges/thread/iter; pos = atomicAdd(rpw[d]) directly.
__global__ void fill_kernel(const void* __restrict__ ei, const int* __restrict__ flag,
                            int* __restrict__ rpw, int* __restrict__ csr_src, int e, int n) {
  int k = blockIdx.x & 7;
  int lo = (int)(((long long)n * k) >> 3);
  int hi = (int)(((long long)n * (k + 1)) >> 3);
  int stride = (gridDim.x >> 3) * 1024;
  int fb64 = *flag;
  for (int i = (blockIdx.x >> 3) * 1024 + threadIdx.x * 4; i < e; i += stride) {
    if (i + 3 < e) {
      int d0, d1, d2, d3;
      if (fb64) {
        ll2 a = *(const ll2*)((const i64*)ei + (size_t)e + i);
        ll2 b2 = *(const ll2*)((const i64*)ei + (size_t)e + i + 2);
        d0 = (int)a.x; d1 = (int)a.y; d2 = (int)b2.x; d3 = (int)b2.y;
      } else {
        int4 dv = *(const int4*)((const int*)ei + (size_t)e + i);
        d0 = dv.x; d1 = dv.y; d2 = dv.z; d3 = dv.w;
      }
      int in0 = (d0 >= lo && d0 < hi), in1 = (d1 >= lo && d1 < hi);
      int in2 = (d2 >= lo && d2 < hi), in3 = (d3 >= lo && d3 < hi);
      if (in0 | in1 | in2 | in3) {
        int s0, s1, s2, s3;
        if (fb64) {
          ll2 sa = *(const ll2*)((const i64*)ei + i);
          ll2 sb = *(const ll2*)((const i64*)ei + i + 2);
          s0 = (int)sa.x; s1 = (int)sa.y; s2 = (int)sb.x; s3 = (int)sb.y;
        } else {
          int4 sv = *(const int4*)((const int*)ei + i);
          s0 = sv.x; s1 = sv.y; s2 = sv.z; s3 = sv.w;
        }
        if (in0) { int pos = atomicAdd(&rpw[d0], 1); csr_src[pos] = s0; }
        if (in1) { int pos = atomicAdd(&rpw[d1], 1); csr_src[pos] = s1; }
        if (in2) { int pos = atomicAdd(&rpw[d2], 1); csr_src[pos] = s2; }
        if (in3) { int pos = atomicAdd(&rpw[d3], 1); csr_src[pos] = s3; }
      }
    } else {
      for (int j = 0; i + j < e; ++j) {
        int d = fb64 ? (int)((const i64*)ei)[(size_t)e + i + j] : ((const int*)ei)[(size_t)e + i + j];
        if (d < lo || d >= hi) continue;
        int s = fb64 ? (int)((const i64*)ei)[i + j] : ((const int*)ei)[i + j];
        int pos = atomicAdd(&rpw[d], 1);
        csr_src[pos] = s;
      }
    }
  }
}

// ---------------- fused BN(from acc stats)+residual + MFMA GEMM, zeroes next acc ----------------

__global__ void __launch_bounds__(256) gemm_bn_kernel(
    const u16* __restrict__ pre, u16* __restrict__ hbuf,
    const float* __restrict__ accIn, float* __restrict__ accZ,
    const void* __restrict__ g, const void* __restrict__ beta, const int* __restrict__ fflag,
    const u16* __restrict__ wfL, const float* __restrict__ dinv,
    u16* __restrict__ u, int n, int use_res, float inv_n, int gOff) {
  __shared__ u16 At[4][2048];   // per-wave A tile in frag order: s*512 + lane*8
  __shared__ float SC[128], SH[128];
  int fb = *fflag;
  if (threadIdx.x < 128) {
    int c = threadIdx.x;
    float s = accIn[c], s2 = accIn[128 + c];
    float mean = s * inv_n;
    float var = s2 * inv_n - mean * mean;
    float sc = ldf(g, (size_t)gOff + c, fb) * rsqrtf(var + EPSV);
    SC[c] = sc;
    SH[c] = ldf(beta, (size_t)gOff + c, fb) - mean * sc;
  }
  if (blockIdx.x == 0) accZ[threadIdx.x] = 0.f;   // 256 floats for upcoming gather stats
  __syncthreads();

  int lane = threadIdx.x & 63;
  int wave = threadIdx.x >> 6;
  int n16 = lane & 15, quad = lane >> 4;
  u16* at = At[wave];
  int node = lane & 15;             // staging row
  int cgrp = lane >> 4;             // staging col group 0..3
  int ntiles = (n + 15) >> 4;
  for (int tile = blockIdx.x * 4 + wave; tile < ntiles; tile += gridDim.x * 4) {
    int n0 = tile * 16;
    int gn = n0 + node;
    // ---- stage hnew tile (frag order), 8 channels (16B) per iter ----
#pragma unroll
    for (int r = 0; r < 4; ++r) {
      int c8 = r * 4 + cgrp;        // 0..15
      int c = c8 * 8;
      uint4 ww = make_uint4(0u, 0u, 0u, 0u);
      if (gn < n) {
        uint4 pv = *(const uint4*)(pre + (size_t)gn * 128 + c);
        unsigned pw[4] = {pv.x, pv.y, pv.z, pv.w};
        float h[8];
#pragma unroll
        for (int m = 0; m < 4; ++m) {
          h[2 * m]     = fmaxf(fmaf(lo2f(pw[m]), SC[c + 2 * m],     SH[c + 2 * m]), 0.f);
          h[2 * m + 1] = fmaxf(fmaf(hi2f(pw[m]), SC[c + 2 * m + 1], SH[c + 2 * m + 1]), 0.f);
        }
        if (use_res) {
          uint4 rv = *(const uint4*)(hbuf + (size_t)gn * 128 + c);
          unsigned rw[4] = {rv.x, rv.y, rv.z, rv.w};
#pragma unroll
          for (int m = 0; m < 4; ++m) {
            h[2 * m] += lo2f(rw[m]); h[2 * m + 1] += hi2f(rw[m]);
          }
        }
        ww.x = pk2(h[0], h[1]); ww.y = pk2(h[2], h[3]);
        ww.z = pk2(h[4], h[5]); ww.w = pk2(h[6], h[7]);
        *(uint4*)(hbuf + (size_t)gn * 128 + c) = ww;
      }
      int c4 = c8 * 2;              // even
      int s = c4 >> 3, qd = (c4 >> 1) & 3;
      *(uint4*)(at + s * 512 + qd * 128 + node * 8) = ww;   // 8 u16 = j 0..7
    }
    __builtin_amdgcn_s_waitcnt(0);  // drain LDS writes (wave-local tile)
    // ---- MFMA: 4 K-steps x 8 col-tiles; B from global wf ----
    f32x4 acc[8];
#pragma unroll
    for (int ct = 0; ct < 8; ++ct) acc[ct] = (f32x4){0.f, 0.f, 0.f, 0.f};
#pragma unroll
    for (int s = 0; s < 4; ++s) {
      bf16x8 af = *(const bf16x8*)(at + s * 512 + lane * 8);
#pragma unroll
      for (int ct = 0; ct < 8; ++ct) {
        bf16x8 bfr = *(const bf16x8*)(wfL + (size_t)(ct * 4 + s) * 512 + lane * 8);
        acc[ct] = __builtin_amdgcn_mfma_f32_16x16x32_bf16(af, bfr, acc[ct], 0, 0, 0);
      }
    }
    // ---- store D scaled by dinv[row], 4-slice-major ----
    float dv[4];
#pragma unroll
    for (int r = 0; r < 4; ++r) {
      int row = n0 + quad * 4 + r;
      dv[r] = (row < n) ? dinv[row] : 0.f;
    }
#pragma unroll
    for (int ct = 0; ct < 8; ++ct) {
#pragma unroll
      for (int r = 0; r < 4; ++r) {
        int row = n0 + quad * 4 + r;
        if (row < n)
          u[((size_t)(ct >> 1) * n + row) * 32 + (ct & 1) * 16 + n16] = f2b(acc[ct][r] * dv[r]);
      }
    }
  }
}

// ---------------- fused gather, 4-slice, dynamic chunks; stats atomicAdd into accOut ----------------

__global__ void __launch_bounds__(256) gather_stats_kernel(
    const int* __restrict__ row_ptr, const int* __restrict__ csr_src,
    const u16* __restrict__ u, const float* __restrict__ dinv,
    const void* __restrict__ b, const int* __restrict__ fflag,
    u16* __restrict__ pre, float* __restrict__ accOut,
    int* __restrict__ wctr, int n, int nch, size_t bOff) {
  __shared__ int sm[WINLEN];
  __shared__ float SW[4][4][8], QW[4][4][8];
  __shared__ int curchunk;
  int fb = *fflag;
  int ct2 = blockIdx.x & 3;
  const u16* us = u + (size_t)ct2 * n * 32;
  int q = threadIdx.x & 3;           // 16B quarter of the 64B node-slice
  int g = threadIdx.x >> 2;          // node group 0..63
  int c = ct2 * 32 + q * 8;          // global channel base
  float bias[8];
#pragma unroll
  for (int i = 0; i < 8; ++i) bias[i] = ldf(b, bOff + c + i, fb);
  float sA[8], qA[8];
#pragma unroll
  for (int i = 0; i < 8; ++i) { sA[i] = 0.f; qA[i] = 0.f; }

  for (;;) {
    __syncthreads();   // prior chunk fully consumed (sm + curchunk)
    if (threadIdx.x == 0) curchunk = atomicAdd(&wctr[ct2], 1);
    __syncthreads();
    int ch = curchunk;
    if (ch >= nch) break;
    int c0 = ch * CHUNK;
    int node = c0 + g;
    int valid = node < n;
    int beg = valid ? row_ptr[node] : 0;
    int end = valid ? row_ptr[node + 1] : 0;
    int cend = c0 + CHUNK; if (cend > n) cend = n;
    int chunk_lo = row_ptr[c0];
    int chunk_hi = row_ptr[cend];
    float acc[8];
    if (valid) {
      uint4 su = *(const uint4*)(us + (size_t)node * 32 + q * 8);
      acc[0] = lo2f(su.x); acc[1] = hi2f(su.x);
      acc[2] = lo2f(su.y); acc[3] = hi2f(su.y);
      acc[4] = lo2f(su.z); acc[5] = hi2f(su.z);
      acc[6] = lo2f(su.w); acc[7] = hi2f(su.w);
    } else {
#pragma unroll
      for (int i = 0; i < 8; ++i) acc[i] = 0.f;
    }
    for (int wlo = chunk_lo; wlo < chunk_hi; wlo += WINLEN) {
      int wlen = chunk_hi - wlo; if (wlen > WINLEN) wlen = WINLEN;
      __syncthreads();   // previous window fully consumed
      for (int i = threadIdx.x; i < wlen; i += 256)
        sm[i] = __builtin_nontemporal_load(csr_src + wlo + i);
      __syncthreads();
      int j0 = beg > wlo ? beg : wlo;
      int j1 = end < wlo + wlen ? end : wlo + wlen;
      int j = j0;
#define ACC(UU) \
      acc[0] += lo2f(UU.x); acc[1] += hi2f(UU.x); \
      acc[2] += lo2f(UU.y); acc[3] += hi2f(UU.y); \
      acc[4] += lo2f(UU.z); acc[5] += hi2f(UU.z); \
      acc[6] += lo2f(UU.w); acc[7] += hi2f(UU.w);
      for (; j + 8 <= j1; j += 8) {
        int i0 = sm[j - wlo],     i1 = sm[j - wlo + 1], i2 = sm[j - wlo + 2], i3 = sm[j - wlo + 3];
        int i4 = sm[j - wlo + 4], i5 = sm[j - wlo + 5], i6 = sm[j - wlo + 6], i7 = sm[j - wlo + 7];
        uint4 U0 = *(const uint4*)(us + (size_t)i0 * 32 + q * 8);
        uint4 U1 = *(const uint4*)(us + (size_t)i1 * 32 + q * 8);
        uint4 U2 = *(const uint4*)(us + (size_t)i2 * 32 + q * 8);
        uint4 U3 = *(const uint4*)(us + (size_t)i3 * 32 + q * 8);
        uint4 U4 = *(const uint4*)(us + (size_t)i4 * 32 + q * 8);
        uint4 U5 = *(const uint4*)(us + (size_t)i5 * 32 + q * 8);
        uint4 U6 = *(const uint4*)(us + (size_t)i6 * 32 + q * 8);
        uint4 U7 = *(const uint4*)(us + (size_t)i7 * 32 + q * 8);
        ACC(U0) ACC(U1) ACC(U2) ACC(U3) ACC(U4) ACC(U5) ACC(U6) ACC(U7)
      }
      for (; j + 4 <= j1; j += 4) {
        int i0 = sm[j - wlo], i1 = sm[j - wlo + 1], i2 = sm[j - wlo + 2], i3 = sm[j - wlo + 3];
        uint4 U0 = *(const uint4*)(us + (size_t)i0 * 32 + q * 8);
        uint4 U1 = *(const uint4*)(us + (size_t)i1 * 32 + q * 8);
        uint4 U2 = *(const uint4*)(us + (size_t)i2 * 32 + q * 8);
        uint4 U3 = *(const uint4*)(us + (size_t)i3 * 32 + q * 8);
        ACC(U0) ACC(U1) ACC(U2) ACC(U3)
      }
      for (; j < j1; ++j) {
        int i0 = sm[j - wlo];
        uint4 U0 = *(const uint4*)(us + (size_t)i0 * 32 + q * 8);
        ACC(U0)
      }
#undef ACC
    }
    if (valid) {
      float dv = dinv[node];
      float o0 = fmaf(acc[0], dv, bias[0]), o1 = fmaf(acc[1], dv, bias[1]);
      float o2 = fmaf(acc[2], dv, bias[2]), o3 = fmaf(acc[3], dv, bias[3]);
      float o4 = fmaf(acc[4], dv, bias[4]), o5 = fmaf(acc[5], dv, bias[5]);
      float o6 = fmaf(acc[6], dv, bias[6]), o7 = fmaf(acc[7], dv, bias[7]);
      unsigned w0 = pk2(o0, o1), w1 = pk2(o2, o3), w2 = pk2(o4, o5), w3 = pk2(o6, o7);
      *(uint4*)(pre + (size_t)node * 128 + c) = make_uint4(w0, w1, w2, w3);
      float r0 = lo2f(w0), r1 = hi2f(w0), r2 = lo2f(w1), r3 = hi2f(w1);
      float r4 = lo2f(w2), r5 = hi2f(w2), r6 = lo2f(w3), r7 = hi2f(w3);
      sA[0] += r0; sA[1] += r1; sA[2] += r2; sA[3] += r3;
      sA[4] += r4; sA[5] += r5; sA[6] += r6; sA[7] += r7;
      qA[0] = fmaf(r0, r0, qA[0]); qA[1] = fmaf(r1, r1, qA[1]);
      qA[2] = fmaf(r2, r2, qA[2]); qA[3] = fmaf(r3, r3, qA[3]);
      qA[4] = fmaf(r4, r4, qA[4]); qA[5] = fmaf(r5, r5, qA[5]);
      qA[6] = fmaf(r6, r6, qA[6]); qA[7] = fmaf(r7, r7, qA[7]);
    }
  }
  // wave butterfly over node-groups (keep q=tid&3 invariant: xor masks multiples of 4)
#pragma unroll
  for (int m = 4; m <= 32; m <<= 1) {
#pragma unroll
    for (int i = 0; i < 8; ++i) {
      sA[i] += __shfl_xor(sA[i], m, 64);
      qA[i] += __shfl_xor(qA[i], m, 64);
    }
  }
  int lane = threadIdx.x & 63, wv = threadIdx.x >> 6;
  if (lane < 4) {
#pragma unroll
    for (int i = 0; i < 8; ++i) { SW[wv][lane][i] = sA[i]; QW[wv][lane][i] = qA[i]; }
  }
  __syncthreads();
  if (threadIdx.x < 32) {
    int qq = threadIdx.x >> 3, i = threadIdx.x & 7;
    float a = SW[0][qq][i] + SW[1][qq][i] + SW[2][qq][i] + SW[3][qq][i];
    float b2 = QW[0][qq][i] + QW[1][qq][i] + QW[2][qq][i] + QW[3][qq][i];
    int chn = ct2 * 32 + qq * 8 + i;
    atomicAdd(&accOut[chn], a);
    atomicAdd(&accOut[128 + chn], b2);
  }
}

// ---------------- fused final: BN-apply + residual + policy MLP + pool + value (last block) ----

__global__ void __launch_bounds__(256) policy_pool_kernel(
    const u16* __restrict__ pre, const u16* __restrict__ hbuf,
    const float* __restrict__ accIn,
    const void* __restrict__ bg, const void* __restrict__ bbeta, int gOff,
    const void* __restrict__ pW1, const void* __restrict__ pb1,
    const void* __restrict__ pW2, const void* __restrict__ pb2,
    const void* __restrict__ vW1, const void* __restrict__ vb1,
    const void* __restrict__ vW2, const void* __restrict__ vb2,
    const int* __restrict__ fflag, float* __restrict__ ppacc, int* __restrict__ pctr,
    void* __restrict__ out, int n, float inv_n) {
  __shared__ float W1[128 * 32];
  __shared__ float B1v[32], W2v[32];
  __shared__ float SC[128], SH[128];
  __shared__ int plast;
  int fb = *fflag;
  for (int i = threadIdx.x; i < 128 * 32; i += 256) W1[i] = ldf(pW1, i, fb);
  if (threadIdx.x < 32) {
    B1v[threadIdx.x] = ldf(pb1, threadIdx.x, fb);
    W2v[threadIdx.x] = ldf(pW2, threadIdx.x, fb);
  }
  if (threadIdx.x < 128) {
    int cch = threadIdx.x;
    float s = accIn[cch], s2 = accIn[128 + cch];
    float mean = s * inv_n;
    float var = s2 * inv_n - mean * mean;
    float sc = ldf(bg, (size_t)gOff + cch, fb) * rsqrtf(var + EPSV);
    SC[cch] = sc;
    SH[cch] = ldf(bbeta, (size_t)gOff + cch, fb) - mean * sc;
  }
  __syncthreads();
  float bias2 = ldf(pb2, 0, fb);
  int q = threadIdx.x & 31, g8 = threadIdx.x >> 5;
  int c = q * 4;
  float4 sc = *(const float4*)&SC[c];
  float4 sh = *(const float4*)&SH[c];
  float cs0 = 0, cs1 = 0, cs2 = 0, cs3 = 0;
  for (int node = blockIdx.x * 8 + g8; node < n; node += gridDim.x * 8) {
    uint2 pv = *(const uint2*)(pre + (size_t)node * 128 + c);
    uint2 rv = *(const uint2*)(hbuf + (size_t)node * 128 + c);
    float4 h4;
    h4.x = fmaxf(fmaf(lo2f(pv.x), sc.x, sh.x), 0.f) + lo2f(rv.x);
    h4.y = fmaxf(fmaf(hi2f(pv.x), sc.y, sh.y), 0.f) + hi2f(rv.x);
    h4.z = fmaxf(fmaf(lo2f(pv.y), sc.z, sh.z), 0.f) + lo2f(rv.y);
    h4.w = fmaxf(fmaf(hi2f(pv.y), sc.w, sh.w), 0.f) + hi2f(rv.y);
    cs0 += h4.x; cs1 += h4.y; cs2 += h4.z; cs3 += h4.w;
    float acc = B1v[q];
#pragma unroll
    for (int k4 = 0; k4 < 32; ++k4) {
      float hx = __shfl(h4.x, k4, 32);
      float hy = __shfl(h4.y, k4, 32);
      float hz = __shfl(h4.z, k4, 32);
      float hw = __shfl(h4.w, k4, 32);
      int k = k4 * 4;
      acc = fmaf(hx, W1[k * 32 + q], acc);
      acc = fmaf(hy, W1[(k + 1) * 32 + q], acc);
      acc = fmaf(hz, W1[(k + 2) * 32 + q], acc);
      acc = fmaf(hw, W1[(k + 3) * 32 + q], acc);
    }
    acc = fmaxf(acc, 0.f) * W2v[q];
    for (int off = 16; off; off >>= 1) acc += __shfl_down(acc, off, 32);
    if (q == 0) {
      float v = acc + bias2;
      if (fb) ((bf16*)out)[node] = __float2bfloat16(v);
      else    ((float*)out)[node] = v;
    }
  }
  __shared__ float4 SS[256];
  SS[threadIdx.x] = make_float4(cs0, cs1, cs2, cs3);
  __syncthreads();
  if (threadIdx.x < 32) {
    float4 a = SS[threadIdx.x];
    for (int g2 = 1; g2 < 8; ++g2) {
      float4 u = SS[g2 * 32 + threadIdx.x];
      a.x += u.x; a.y += u.y; a.z += u.z; a.w += u.w;
    }
    int cc = threadIdx.x * 4;
    atomicAdd(&ppacc[cc + 0], a.x); atomicAdd(&ppacc[cc + 1], a.y);
    atomicAdd(&ppacc[cc + 2], a.z); atomicAdd(&ppacc[cc + 3], a.w);
  }
  __syncthreads();   // all this block's ppacc adds performed before counter bump
  if (threadIdx.x == 0) {
    int old = atomicAdd(pctr, 1);
    plast = (old == (int)gridDim.x - 1) ? 1 : 0;
  }
  __syncthreads();
  if (plast) {
    __shared__ float gs[128];
    if (threadIdx.x < 128) gs[threadIdx.x] = atomicAdd(&ppacc[threadIdx.x], 0.f);  // coherent read
    __syncthreads();
    if (threadIdx.x < 64) {
      int cc = threadIdx.x;
      float acc2 = ldf(vb1, cc, fb);
      for (int k = 0; k < 128; ++k)
        acc2 = fmaf(gs[k] * inv_n, ldf(vW1, (size_t)k * 64 + cc, fb), acc2);
      acc2 = fmaxf(acc2, 0.f);
      float v = acc2 * ldf(vW2, cc, fb);
      for (int off = 32; off; off >>= 1) v += __shfl_down(v, off, 64);
      if (cc == 0) {
        float rr = tanhf(v + ldf(vb2, 0, fb));
        if (fb) ((bf16*)out)[n] = __float2bfloat16(rr);
        else    ((float*)out)[n] = rr;
      }
    }
  }
}

// ---------------- host ----------------

extern "C" void kernel_launch(void* const* d_in, const int* in_sizes, int n_in,
                              void* d_out, int out_size, void* d_ws, size_t ws_size,
                              hipStream_t stream) {
  const void* x       = d_in[0];
  const void* ei      = d_in[1];
  const void* in_W    = d_in[3];
  const void* in_b    = d_in[4];
  const void* in_g    = d_in[5];
  const void* in_beta = d_in[6];
  const void* conv_W  = d_in[7];
  const void* conv_b  = d_in[8];
  const void* bn_g    = d_in[9];
  const void* bn_beta = d_in[10];
  const void* pW1     = d_in[11];
  const void* pb1     = d_in[12];
  const void* pW2     = d_in[13];
  const void* pb2     = d_in[14];
  const void* vW1     = d_in[15];
  const void* vb1     = d_in[16];
  const void* vW2     = d_in[17];
  const void* vb2     = d_in[18];

  const int H = 128;
  int in_dim = in_sizes[3] / H;        // 5
  int n      = in_sizes[0] / in_dim;   // 100000
  int e      = in_sizes[1] / 2;        // 3200000
  int L      = in_sizes[7] / (H * H);  // 6

  const int GS  = 2048;  // gather grid (multiple of 4)
  const int GI  = 512;   // inproj grid (multiple of 8 -> deg XCD affinity preserved)
  const int GP  = 1024;  // policy grid
  const int GF  = 2048;  // deg/fill grid (multiple of 8)

  char* w = (char*)d_ws;
  u16*   u    = (u16*)w;   w += (size_t)n * H * sizeof(u16);
  u16*   pre  = (u16*)w;   w += (size_t)n * H * sizeof(u16);
  u16*   hbuf = (u16*)w;   w += (size_t)n * H * sizeof(u16);
  int*   csr_src  = (int*)w;   w += ((size_t)e + 16) * sizeof(int);
  int*   row_ptr  = (int*)w;   w += (size_t)(n + 1 + 15) / 16 * 16 * sizeof(int);
  int*   degcnt   = (int*)w;   w += (size_t)n * sizeof(int);
  int*   rpw      = (int*)w;   w += (size_t)n * sizeof(int);
  float* dinv     = (float*)w; w += (size_t)n * sizeof(float);
  int*   eflag = (int*)w;   w += 16 * sizeof(int);
  int*   fflag = (int*)w;   w += 16 * sizeof(int);
  int*   bsum  = (int*)w;   w += 256 * sizeof(int);
  int*   wctr  = (int*)w;   w += 32 * sizeof(int);   // 6 layers x 4 slices dynamic counters
  int*   pctr  = (int*)w;   w += 16 * sizeof(int);
  float* buf0  = (float*)w; w += 256 * sizeof(float);
  float* buf1  = (float*)w; w += 256 * sizeof(float);
  float* ppacc = (float*)w; w += 128 * sizeof(float);
  u16*   wf    = (u16*)w;   w += (size_t)L * H * H * sizeof(u16);

  int gN = (n + 255) / 256;
  int nb = (n + 1023) >> 10;
  int nch = (n + CHUNK - 1) / CHUNK;
  int wtotal = L * H * H;
  int GW = (wtotal + 255) / 256;
  float inv_n = 1.0f / (float)n;
  float* bufs[2] = {buf0, buf1};

  setup_kernel<<<gN, 256, 0, stream>>>((const int*)ei, (const unsigned int*)in_g,
                                       eflag, fflag, degcnt, wctr, pctr,
                                       buf0, buf1, ppacc, n);
  pre_merged_kernel<<<GI + GF + GW, 256, 0, stream>>>(
      x, in_W, in_b, ei, conv_W, eflag, fflag, degcnt, pre, buf0, wf,
      n, in_dim, e, wtotal, GI, GF);
  scanA_kernel<<<nb, 256, 0, stream>>>(degcnt, row_ptr, bsum, dinv, n);
  scanB_kernel<<<1, 256, 0, stream>>>(bsum, row_ptr, nb, n, e);
  scanC_kernel<<<gN, 256, 0, stream>>>(row_ptr, bsum, rpw, n);
  fill_kernel<<<GF, 256, 0, stream>>>(ei, eflag, rpw, csr_src, e, n);

  for (int l = 0; l < L; ++l) {
    const void* g    = (l == 0) ? in_g    : bn_g;
    const void* beta = (l == 0) ? in_beta : bn_beta;
    int gOff = (l == 0) ? 0 : (l - 1) * H;
    gemm_bn_kernel<<<2048, 256, 0, stream>>>(pre, hbuf, bufs[l & 1], bufs[(l + 1) & 1],
                                             g, beta, fflag, wf + (size_t)l * H * H,
                                             dinv, u, n, (l > 0) ? 1 : 0, inv_n, gOff);
    gather_stats_kernel<<<GS, 256, 0, stream>>>(row_ptr, csr_src, u, dinv,
                                                conv_b, fflag, pre, bufs[(l + 1) & 1],
                                                wctr + l * 4, n, nch, (size_t)l * H);
  }

  policy_pool_kernel<<<GP, 256, 0, stream>>>(pre, hbuf, bufs[L & 1],
                                             bn_g, bn_beta, (L - 1) * H,
                                             pW1, pb1, pW2, pb2, vW1, vb1, vW2, vb2,
                                             fflag, ppacc, pctr, d_out, n, inv_n);
}

// Round 9
// 1538.473 us; speedup vs baseline: 1.1576x; 1.0903x over previous
//
#include <hip/hip_runtime.h>
#include <hip/hip_bf16.h>

typedef __hip_bfloat16 bf16;
typedef long long i64;
typedef unsigned short u16;
typedef __attribute__((ext_vector_type(8))) short bf16x8;   // MFMA A/B frag (8 bf16)
typedef __attribute__((ext_vector_type(4))) float f32x4;    // MFMA C/D frag
typedef __attribute__((ext_vector_type(2))) long long ll2;  // 2x int64 edge load

#define EPSV 1e-5f
#define WINLEN 2560
#define CHUNK 64
#define NREP 8        // stat-accumulator replicas (cuts atomic serialization 8x)

static __device__ __forceinline__ float ldf(const void* p, size_t i, int fb) {
  return fb ? __bfloat162float(((const bf16*)p)[i]) : ((const float*)p)[i];
}
static __device__ __forceinline__ u16 f2b(float f) {  // RNE f32->bf16 raw bits
  unsigned int u = __float_as_uint(f);
  u += 0x7FFF + ((u >> 16) & 1);
  return (u16)(u >> 16);
}
static __device__ __forceinline__ unsigned pk2(float a, float b) {  // 2x bf16 in one u32
  return (unsigned)f2b(a) | ((unsigned)f2b(b) << 16);
}
static __device__ __forceinline__ float lo2f(unsigned w) { return __uint_as_float(w << 16); }
static __device__ __forceinline__ float hi2f(unsigned w) { return __uint_as_float(w & 0xFFFF0000u); }

// ---------------- merged detectors + zero-init ----------------

__global__ void setup_kernel(const int* __restrict__ ei_w, const unsigned int* __restrict__ g,
                             int* __restrict__ eflag, int* __restrict__ fflag,
                             int* __restrict__ degcnt,
                             int* __restrict__ wctr, int* __restrict__ pctr,
                             float* __restrict__ buf0, float* __restrict__ buf1,
                             float* __restrict__ ppacc, int n) {
  int i = blockIdx.x * 256 + threadIdx.x;
  if (i < n) degcnt[i] = 0;
  if (blockIdx.x == 0) {
    __shared__ int nz;
    if (threadIdx.x == 0) { nz = 0; *pctr = 0; }
    if (threadIdx.x < 32) wctr[threadIdx.x] = 0;   // dynamic-chunk counters (6 layers x 4 slices)
    for (int k = threadIdx.x; k < NREP * 256; k += 256) { buf0[k] = 0.f; buf1[k] = 0.f; }
    for (int k = threadIdx.x; k < NREP * 128; k += 256) ppacc[k] = 0.f;
    __syncthreads();
    for (int k = threadIdx.x; k < 1024; k += 256)
      if (ei_w[2 * k + 1] != 0) atomicAdd(&nz, 1);
    __syncthreads();
    if (threadIdx.x == 0) {
      *eflag = (nz == 0) ? 1 : 0;                 // 1 => int64
      *fflag = (g[0] == 0x3F803F80u) ? 1 : 0;     // 1 => bf16
    }
  }
}

// ---------------- merged independent preprocessing: inproj | deg | wfrag ----------------
// deg: scalar XCD dst-partitioned 8-slice (measured-best). Stats -> replicated acc.

__global__ void __launch_bounds__(256) pre_merged_kernel(
    const void* __restrict__ x, const void* __restrict__ W, const void* __restrict__ b,
    const void* __restrict__ ei, const void* __restrict__ convW,
    const int* __restrict__ eflag, const int* __restrict__ fflag,
    int* __restrict__ degcnt, u16* __restrict__ pre, float* __restrict__ acc0,
    u16* __restrict__ wf, int n, int in_dim, int e, int wtotal, int gi, int gf) {
  __shared__ float4 SS[256], QQ[256];
  int fb = *fflag;
  if ((int)blockIdx.x < gi) {
    // ---- input projection + BN partial stats ----
    int q = threadIdx.x & 31, g8 = threadIdx.x >> 5;
    int c = q * 4;
    float b0 = ldf(b, c, fb), b1 = ldf(b, c + 1, fb), b2v = ldf(b, c + 2, fb), b3 = ldf(b, c + 3, fb);
    float s0 = 0, s1 = 0, s2 = 0, s3 = 0, q0 = 0, q1 = 0, q2 = 0, q3 = 0;
    for (int node = blockIdx.x * 8 + g8; node < n; node += gi * 8) {
      float a0 = b0, a1 = b1, a2 = b2v, a3 = b3;
      for (int k = 0; k < in_dim; ++k) {
        float xv = ldf(x, (size_t)node * in_dim + k, fb);
        size_t w0 = (size_t)k * 128 + c;
        a0 = fmaf(xv, ldf(W, w0, fb), a0);
        a1 = fmaf(xv, ldf(W, w0 + 1, fb), a1);
        a2 = fmaf(xv, ldf(W, w0 + 2, fb), a2);
        a3 = fmaf(xv, ldf(W, w0 + 3, fb), a3);
      }
      unsigned w0p = pk2(a0, a1), w1p = pk2(a2, a3);
      *(uint2*)(pre + (size_t)node * 128 + c) = make_uint2(w0p, w1p);
      float r0 = lo2f(w0p), r1 = hi2f(w0p), r2 = lo2f(w1p), r3 = hi2f(w1p);
      s0 += r0; s1 += r1; s2 += r2; s3 += r3;
      q0 = fmaf(r0, r0, q0); q1 = fmaf(r1, r1, q1); q2 = fmaf(r2, r2, q2); q3 = fmaf(r3, r3, q3);
    }
    SS[threadIdx.x] = make_float4(s0, s1, s2, s3);
    QQ[threadIdx.x] = make_float4(q0, q1, q2, q3);
    __syncthreads();
    if (threadIdx.x < 32) {
      float4 a = SS[threadIdx.x], qq = QQ[threadIdx.x];
      for (int g2 = 1; g2 < 8; ++g2) {
        float4 u = SS[g2 * 32 + threadIdx.x], w = QQ[g2 * 32 + threadIdx.x];
        a.x += u.x; a.y += u.y; a.z += u.z; a.w += u.w;
        qq.x += w.x; qq.y += w.y; qq.z += w.z; qq.w += w.w;
      }
      float* ar = acc0 + (blockIdx.x & (NREP - 1)) * 256;
      int cc = threadIdx.x * 4;
      atomicAdd(&ar[cc + 0], a.x); atomicAdd(&ar[cc + 1], a.y);
      atomicAdd(&ar[cc + 2], a.z); atomicAdd(&ar[cc + 3], a.w);
      atomicAdd(&ar[128 + cc + 0], qq.x); atomicAdd(&ar[128 + cc + 1], qq.y);
      atomicAdd(&ar[128 + cc + 2], qq.z); atomicAdd(&ar[128 + cc + 3], qq.w);
    }
  } else if ((int)blockIdx.x < gi + gf) {
    // ---- degree count, XCD dst-partitioned, scalar ----
    int bid = blockIdx.x - gi;
    int k = bid & 7;
    int lo = (int)(((long long)n * k) >> 3);
    int hi = (int)(((long long)n * (k + 1)) >> 3);
    int stride = (gf >> 3) * 256;
    int fb64 = *eflag;
    for (int i = (bid >> 3) * 256 + threadIdx.x; i < e; i += stride) {
      int d;
      if (fb64) d = (int)((const i64*)ei)[(size_t)e + i];
      else      d = ((const int*)ei)[(size_t)e + i];
      if (d >= lo && d < hi) atomicAdd(&degcnt[d], 1);
    }
  } else {
    // ---- conv_W -> global B-frag order (bf16) ----
    int bid = blockIdx.x - gi - gf;
    int i = bid * 256 + threadIdx.x;
    if (i < wtotal) {
      int l = i >> 14, r = i & 16383;
      int k = r >> 7, nn = r & 127;
      int s = k >> 5, quad = (k >> 3) & 3, j = k & 7;
      int ct = nn >> 4, n16 = nn & 15;
      wf[(size_t)l * 16384 + (ct * 4 + s) * 512 + quad * 128 + n16 * 8 + j] = f2b(ldf(convW, i, fb));
    }
  }
}

// ---- multi-block exclusive scan (dinv folded into A) ----

__global__ void __launch_bounds__(256) scanA_kernel(const int* __restrict__ deg,
                                                    int* __restrict__ rp,
                                                    int* __restrict__ bsum,
                                                    float* __restrict__ dinv, int n) {
  int base = blockIdx.x * 1024 + threadIdx.x * 4;
  int v0 = (base     < n) ? deg[base]     : 0;
  int v1 = (base + 1 < n) ? deg[base + 1] : 0;
  int v2 = (base + 2 < n) ? deg[base + 2] : 0;
  int v3 = (base + 3 < n) ? deg[base + 3] : 0;
  if (base     < n) dinv[base]     = rsqrtf((float)v0 + 1.0f);
  if (base + 1 < n) dinv[base + 1] = rsqrtf((float)v1 + 1.0f);
  if (base + 2 < n) dinv[base + 2] = rsqrtf((float)v2 + 1.0f);
  if (base + 3 < n) dinv[base + 3] = rsqrtf((float)v3 + 1.0f);
  int ts = v0 + v1 + v2 + v3;
  __shared__ int ls[256];
  ls[threadIdx.x] = ts;
  __syncthreads();
  for (int off = 1; off < 256; off <<= 1) {
    int u = (threadIdx.x >= off) ? ls[threadIdx.x - off] : 0;
    __syncthreads();
    ls[threadIdx.x] += u;
    __syncthreads();
  }
  int run = ls[threadIdx.x] - ts;
  if (base     < n) rp[base]     = run; run += v0;
  if (base + 1 < n) rp[base + 1] = run; run += v1;
  if (base + 2 < n) rp[base + 2] = run; run += v2;
  if (base + 3 < n) rp[base + 3] = run;
  if (threadIdx.x == 255) bsum[blockIdx.x] = ls[255];
}

__global__ void __launch_bounds__(256) scanB_kernel(int* __restrict__ bsum, int* __restrict__ rp,
                                                    int nb, int n, int e) {
  __shared__ int ls[256];
  int t = threadIdx.x;
  int v = (t < nb) ? bsum[t] : 0;
  ls[t] = v;
  __syncthreads();
  for (int off = 1; off < 256; off <<= 1) {
    int u = (t >= off) ? ls[t - off] : 0;
    __syncthreads();
    ls[t] += u;
    __syncthreads();
  }
  if (t < nb) bsum[t] = ls[t] - v;  // exclusive
  if (t == 0) rp[n] = e;
}

// fixup + write rpw copy (fill's direct-allocation counters).
__global__ void scanC_kernel(int* __restrict__ rp, const int* __restrict__ bsum,
                             int* __restrict__ rpw, int n) {
  int i = blockIdx.x * 256 + threadIdx.x;
  if (i < n) {
    int v = rp[i] + bsum[i >> 10];
    rp[i] = v;
    rpw[i] = v;
  }
}

// XCD dst-partitioned fill, 4 edges/thread/iter; pos = atomicAdd(rpw[d]) directly.
__global__ void fill_kernel(const void* __restrict__ ei, const int* __restrict__ flag,
                            int* __restrict__ rpw, int* __restrict__ csr_src, int e, int n) {
  int k = blockIdx.x & 7;
  int lo = (int)(((long long)n * k) >> 3);
  int hi = (int)(((long long)n * (k + 1)) >> 3);
  int stride = (gridDim.x >> 3) * 1024;
  int fb64 = *flag;
  for (int i = (blockIdx.x >> 3) * 1024 + threadIdx.x * 4; i < e; i += stride) {
    if (i + 3 < e) {
      int d0, d1, d2, d3;
      if (fb64) {
        ll2 a = *(const ll2*)((const i64*)ei + (size_t)e + i);
        ll2 b2 = *(const ll2*)((const i64*)ei + (size_t)e + i + 2);
        d0 = (int)a.x; d1 = (int)a.y; d2 = (int)b2.x; d3 = (int)b2.y;
      } else {
        int4 dv = *(const int4*)((const int*)ei + (size_t)e + i);
        d0 = dv.x; d1 = dv.y; d2 = dv.z; d3 = dv.w;
      }
      int in0 = (d0 >= lo && d0 < hi), in1 = (d1 >= lo && d1 < hi);
      int in2 = (d2 >= lo && d2 < hi), in3 = (d3 >= lo && d3 < hi);
      if (in0 | in1 | in2 | in3) {
        int s0, s1, s2, s3;
        if (fb64) {
          ll2 sa = *(const ll2*)((const i64*)ei + i);
          ll2 sb = *(const ll2*)((const i64*)ei + i + 2);
          s0 = (int)sa.x; s1 = (int)sa.y; s2 = (int)sb.x; s3 = (int)sb.y;
        } else {
          int4 sv = *(const int4*)((const int*)ei + i);
          s0 = sv.x; s1 = sv.y; s2 = sv.z; s3 = sv.w;
        }
        if (in0) { int pos = atomicAdd(&rpw[d0], 1); csr_src[pos] = s0; }
        if (in1) { int pos = atomicAdd(&rpw[d1], 1); csr_src[pos] = s1; }
        if (in2) { int pos = atomicAdd(&rpw[d2], 1); csr_src[pos] = s2; }
        if (in3) { int pos = atomicAdd(&rpw[d3], 1); csr_src[pos] = s3; }
      }
    } else {
      for (int j = 0; i + j < e; ++j) {
        int d = fb64 ? (int)((const i64*)ei)[(size_t)e + i + j] : ((const int*)ei)[(size_t)e + i + j];
        if (d < lo || d >= hi) continue;
        int s = fb64 ? (int)((const i64*)ei)[i + j] : ((const int*)ei)[i + j];
        int pos = atomicAdd(&rpw[d], 1);
        csr_src[pos] = s;
      }
    }
  }
}

// ---------------- fused BN(from replicated acc stats)+residual + MFMA GEMM ----------------
// u-store now coalesced: D fragments -> LDS [pair][node][32] -> 16B/lane contiguous stores
// (was 32 scalar 2B stores/lane -> ~4 scattered 32B transactions per wave-store).

__global__ void __launch_bounds__(256) gemm_bn_kernel(
    const u16* __restrict__ pre, u16* __restrict__ hbuf,
    const float* __restrict__ accIn, float* __restrict__ accZ,
    const void* __restrict__ g, const void* __restrict__ beta, const int* __restrict__ fflag,
    const u16* __restrict__ wfL, const float* __restrict__ dinv,
    u16* __restrict__ u, int n, int use_res, float inv_n, int gOff) {
  __shared__ u16 At[4][2048];   // per-wave A tile in frag order; reused for D transpose
  __shared__ float SC[128], SH[128];
  int fb = *fflag;
  if (threadIdx.x < 128) {
    int c = threadIdx.x;
    float s = 0.f, s2 = 0.f;
#pragma unroll
    for (int r = 0; r < NREP; ++r) {
      s  += accIn[r * 256 + c];
      s2 += accIn[r * 256 + 128 + c];
    }
    float mean = s * inv_n;
    float var = s2 * inv_n - mean * mean;
    float sc = ldf(g, (size_t)gOff + c, fb) * rsqrtf(var + EPSV);
    SC[c] = sc;
    SH[c] = ldf(beta, (size_t)gOff + c, fb) - mean * sc;
  }
  if (blockIdx.x == 0)
    for (int i = threadIdx.x; i < NREP * 256; i += 256) accZ[i] = 0.f;
  __syncthreads();

  int lane = threadIdx.x & 63;
  int wave = threadIdx.x >> 6;
  int n16 = lane & 15, quad = lane >> 4;
  u16* at = At[wave];
  int node = lane & 15;             // staging row
  int cgrp = lane >> 4;             // staging col group 0..3
  int ntiles = (n + 15) >> 4;
  for (int tile = blockIdx.x * 4 + wave; tile < ntiles; tile += gridDim.x * 4) {
    int n0 = tile * 16;
    int gn = n0 + node;
    // ---- stage hnew tile (frag order), 8 channels (16B) per iter ----
#pragma unroll
    for (int r = 0; r < 4; ++r) {
      int c8 = r * 4 + cgrp;        // 0..15
      int c = c8 * 8;
      uint4 ww = make_uint4(0u, 0u, 0u, 0u);
      if (gn < n) {
        uint4 pv = *(const uint4*)(pre + (size_t)gn * 128 + c);
        unsigned pw[4] = {pv.x, pv.y, pv.z, pv.w};
        float h[8];
#pragma unroll
        for (int m = 0; m < 4; ++m) {
          h[2 * m]     = fmaxf(fmaf(lo2f(pw[m]), SC[c + 2 * m],     SH[c + 2 * m]), 0.f);
          h[2 * m + 1] = fmaxf(fmaf(hi2f(pw[m]), SC[c + 2 * m + 1], SH[c + 2 * m + 1]), 0.f);
        }
        if (use_res) {
          uint4 rv = *(const uint4*)(hbuf + (size_t)gn * 128 + c);
          unsigned rw[4] = {rv.x, rv.y, rv.z, rv.w};
#pragma unroll
          for (int m = 0; m < 4; ++m) {
            h[2 * m] += lo2f(rw[m]); h[2 * m + 1] += hi2f(rw[m]);
          }
        }
        ww.x = pk2(h[0], h[1]); ww.y = pk2(h[2], h[3]);
        ww.z = pk2(h[4], h[5]); ww.w = pk2(h[6], h[7]);
        *(uint4*)(hbuf + (size_t)gn * 128 + c) = ww;
      }
      int c4 = c8 * 2;              // even
      int s = c4 >> 3, qd = (c4 >> 1) & 3;
      *(uint4*)(at + s * 512 + qd * 128 + node * 8) = ww;   // 8 u16 = j 0..7
    }
    __builtin_amdgcn_s_waitcnt(0);  // drain LDS writes (wave-local tile)
    // ---- MFMA: 4 K-steps x 8 col-tiles; B from global wf ----
    f32x4 acc[8];
#pragma unroll
    for (int ct = 0; ct < 8; ++ct) acc[ct] = (f32x4){0.f, 0.f, 0.f, 0.f};
#pragma unroll
    for (int s = 0; s < 4; ++s) {
      bf16x8 af = *(const bf16x8*)(at + s * 512 + lane * 8);
#pragma unroll
      for (int ct = 0; ct < 8; ++ct) {
        bf16x8 bfr = *(const bf16x8*)(wfL + (size_t)(ct * 4 + s) * 512 + lane * 8);
        acc[ct] = __builtin_amdgcn_mfma_f32_16x16x32_bf16(af, bfr, acc[ct], 0, 0, 0);
      }
    }
    // ---- D*dinv -> LDS [pair][node16][32] (wave-local; DS ops in-order per wave) ----
    float dv[4];
#pragma unroll
    for (int r = 0; r < 4; ++r) {
      int row = n0 + quad * 4 + r;
      dv[r] = (row < n) ? dinv[row] : 0.f;
    }
#pragma unroll
    for (int ct = 0; ct < 8; ++ct) {
#pragma unroll
      for (int r = 0; r < 4; ++r) {
        at[(ct >> 1) * 512 + (quad * 4 + r) * 32 + (ct & 1) * 16 + n16] = f2b(acc[ct][r] * dv[r]);
      }
    }
    __builtin_amdgcn_s_waitcnt(0);
    // ---- coalesced u store: 4 iters x 16B/lane, 1KB contiguous per (iter,pair) ----
#pragma unroll
    for (int it = 0; it < 4; ++it) {
      int f = it * 512 + lane * 8;       // u16 flat index; pair = it
      int nd = (f >> 5) & 15;            // node within tile
      int ch = f & 31;
      int row = n0 + nd;
      if (row < n) {
        uint4 vv = *(const uint4*)(at + f);
        *(uint4*)(u + ((size_t)it * n + row) * 32 + ch) = vv;
      }
    }
  }
}

// ---------------- fused gather, 4-slice, dynamic chunks; stats -> replicated accOut ----------------

__global__ void __launch_bounds__(256) gather_stats_kernel(
    const int* __restrict__ row_ptr, const int* __restrict__ csr_src,
    const u16* __restrict__ u, const float* __restrict__ dinv,
    const void* __restrict__ b, const int* __restrict__ fflag,
    u16* __restrict__ pre, float* __restrict__ accOut,
    int* __restrict__ wctr, int n, int nch, size_t bOff) {
  __shared__ int sm[WINLEN];
  __shared__ float SW[4][4][8], QW[4][4][8];
  __shared__ int curchunk;
  int fb = *fflag;
  int ct2 = blockIdx.x & 3;
  const u16* us = u + (size_t)ct2 * n * 32;
  int q = threadIdx.x & 3;           // 16B quarter of the 64B node-slice
  int g = threadIdx.x >> 2;          // node group 0..63
  int c = ct2 * 32 + q * 8;          // global channel base
  float bias[8];
#pragma unroll
  for (int i = 0; i < 8; ++i) bias[i] = ldf(b, bOff + c + i, fb);
  float sA[8], qA[8];
#pragma unroll
  for (int i = 0; i < 8; ++i) { sA[i] = 0.f; qA[i] = 0.f; }

  for (;;) {
    __syncthreads();   // prior chunk fully consumed (sm + curchunk)
    if (threadIdx.x == 0) curchunk = atomicAdd(&wctr[ct2], 1);
    __syncthreads();
    int ch = curchunk;
    if (ch >= nch) break;
    int c0 = ch * CHUNK;
    int node = c0 + g;
    int valid = node < n;
    int beg = valid ? row_ptr[node] : 0;
    int end = valid ? row_ptr[node + 1] : 0;
    int cend = c0 + CHUNK; if (cend > n) cend = n;
    int chunk_lo = row_ptr[c0];
    int chunk_hi = row_ptr[cend];
    float acc[8];
    if (valid) {
      uint4 su = *(const uint4*)(us + (size_t)node * 32 + q * 8);
      acc[0] = lo2f(su.x); acc[1] = hi2f(su.x);
      acc[2] = lo2f(su.y); acc[3] = hi2f(su.y);
      acc[4] = lo2f(su.z); acc[5] = hi2f(su.z);
      acc[6] = lo2f(su.w); acc[7] = hi2f(su.w);
    } else {
#pragma unroll
      for (int i = 0; i < 8; ++i) acc[i] = 0.f;
    }
    for (int wlo = chunk_lo; wlo < chunk_hi; wlo += WINLEN) {
      int wlen = chunk_hi - wlo; if (wlen > WINLEN) wlen = WINLEN;
      __syncthreads();   // previous window fully consumed
      for (int i = threadIdx.x; i < wlen; i += 256)
        sm[i] = __builtin_nontemporal_load(csr_src + wlo + i);
      __syncthreads();
      int j0 = beg > wlo ? beg : wlo;
      int j1 = end < wlo + wlen ? end : wlo + wlen;
      int j = j0;
#define ACC(UU) \
      acc[0] += lo2f(UU.x); acc[1] += hi2f(UU.x); \
      acc[2] += lo2f(UU.y); acc[3] += hi2f(UU.y); \
      acc[4] += lo2f(UU.z); acc[5] += hi2f(UU.z); \
      acc[6] += lo2f(UU.w); acc[7] += hi2f(UU.w);
      for (; j + 8 <= j1; j += 8) {
        int i0 = sm[j - wlo],     i1 = sm[j - wlo + 1], i2 = sm[j - wlo + 2], i3 = sm[j - wlo + 3];
        int i4 = sm[j - wlo + 4], i5 = sm[j - wlo + 5], i6 = sm[j - wlo + 6], i7 = sm[j - wlo + 7];
        uint4 U0 = *(const uint4*)(us + (size_t)i0 * 32 + q * 8);
        uint4 U1 = *(const uint4*)(us + (size_t)i1 * 32 + q * 8);
        uint4 U2 = *(const uint4*)(us + (size_t)i2 * 32 + q * 8);
        uint4 U3 = *(const uint4*)(us + (size_t)i3 * 32 + q * 8);
        uint4 U4 = *(const uint4*)(us + (size_t)i4 * 32 + q * 8);
        uint4 U5 = *(const uint4*)(us + (size_t)i5 * 32 + q * 8);
        uint4 U6 = *(const uint4*)(us + (size_t)i6 * 32 + q * 8);
        uint4 U7 = *(const uint4*)(us + (size_t)i7 * 32 + q * 8);
        ACC(U0) ACC(U1) ACC(U2) ACC(U3) ACC(U4) ACC(U5) ACC(U6) ACC(U7)
      }
      for (; j + 4 <= j1; j += 4) {
        int i0 = sm[j - wlo], i1 = sm[j - wlo + 1], i2 = sm[j - wlo + 2], i3 = sm[j - wlo + 3];
        uint4 U0 = *(const uint4*)(us + (size_t)i0 * 32 + q * 8);
        uint4 U1 = *(const uint4*)(us + (size_t)i1 * 32 + q * 8);
        uint4 U2 = *(const uint4*)(us + (size_t)i2 * 32 + q * 8);
        uint4 U3 = *(const uint4*)(us + (size_t)i3 * 32 + q * 8);
        ACC(U0) ACC(U1) ACC(U2) ACC(U3)
      }
      for (; j < j1; ++j) {
        int i0 = sm[j - wlo];
        uint4 U0 = *(const uint4*)(us + (size_t)i0 * 32 + q * 8);
        ACC(U0)
      }
#undef ACC
    }
    if (valid) {
      float dv = dinv[node];
      float o0 = fmaf(acc[0], dv, bias[0]), o1 = fmaf(acc[1], dv, bias[1]);
      float o2 = fmaf(acc[2], dv, bias[2]), o3 = fmaf(acc[3], dv, bias[3]);
      float o4 = fmaf(acc[4], dv, bias[4]), o5 = fmaf(acc[5], dv, bias[5]);
      float o6 = fmaf(acc[6], dv, bias[6]), o7 = fmaf(acc[7], dv, bias[7]);
      unsigned w0 = pk2(o0, o1), w1 = pk2(o2, o3), w2 = pk2(o4, o5), w3 = pk2(o6, o7);
      *(uint4*)(pre + (size_t)node * 128 + c) = make_uint4(w0, w1, w2, w3);
      float r0 = lo2f(w0), r1 = hi2f(w0), r2 = lo2f(w1), r3 = hi2f(w1);
      float r4 = lo2f(w2), r5 = hi2f(w2), r6 = lo2f(w3), r7 = hi2f(w3);
      sA[0] += r0; sA[1] += r1; sA[2] += r2; sA[3] += r3;
      sA[4] += r4; sA[5] += r5; sA[6] += r6; sA[7] += r7;
      qA[0] = fmaf(r0, r0, qA[0]); qA[1] = fmaf(r1, r1, qA[1]);
      qA[2] = fmaf(r2, r2, qA[2]); qA[3] = fmaf(r3, r3, qA[3]);
      qA[4] = fmaf(r4, r4, qA[4]); qA[5] = fmaf(r5, r5, qA[5]);
      qA[6] = fmaf(r6, r6, qA[6]); qA[7] = fmaf(r7, r7, qA[7]);
    }
  }
  // wave butterfly over node-groups (keep q=tid&3 invariant: xor masks multiples of 4)
#pragma unroll
  for (int m = 4; m <= 32; m <<= 1) {
#pragma unroll
    for (int i = 0; i < 8; ++i) {
      sA[i] += __shfl_xor(sA[i], m, 64);
      qA[i] += __shfl_xor(qA[i], m, 64);
    }
  }
  int lane = threadIdx.x & 63, wv = threadIdx.x >> 6;
  if (lane < 4) {
#pragma unroll
    for (int i = 0; i < 8; ++i) { SW[wv][lane][i] = sA[i]; QW[wv][lane][i] = qA[i]; }
  }
  __syncthreads();
  if (threadIdx.x < 32) {
    int qq = threadIdx.x >> 3, i = threadIdx.x & 7;
    float a = SW[0][qq][i] + SW[1][qq][i] + SW[2][qq][i] + SW[3][qq][i];
    float b2 = QW[0][qq][i] + QW[1][qq][i] + QW[2][qq][i] + QW[3][qq][i];
    int chn = ct2 * 32 + qq * 8 + i;
    float* ar = accOut + (blockIdx.x & (NREP - 1)) * 256;
    atomicAdd(&ar[chn], a);
    atomicAdd(&ar[128 + chn], b2);
  }
}

// ---------------- fused final: BN-apply + residual + policy MLP + pool + value (last block) ----

__global__ void __launch_bounds__(256) policy_pool_kernel(
    const u16* __restrict__ pre, const u16* __restrict__ hbuf,
    const float* __restrict__ accIn,
    const void* __restrict__ bg, const void* __restrict__ bbeta, int gOff,
    const void* __restrict__ pW1, const void* __restrict__ pb1,
    const void* __restrict__ pW2, const void* __restrict__ pb2,
    const void* __restrict__ vW1, const void* __restrict__ vb1,
    const void* __restrict__ vW2, const void* __restrict__ vb2,
    const int* __restrict__ fflag, float* __restrict__ ppacc, int* __restrict__ pctr,
    void* __restrict__ out, int n, float inv_n) {
  __shared__ float W1[128 * 32];
  __shared__ float B1v[32], W2v[32];
  __shared__ float SC[128], SH[128];
  __shared__ int plast;
  int fb = *fflag;
  for (int i = threadIdx.x; i < 128 * 32; i += 256) W1[i] = ldf(pW1, i, fb);
  if (threadIdx.x < 32) {
    B1v[threadIdx.x] = ldf(pb1, threadIdx.x, fb);
    W2v[threadIdx.x] = ldf(pW2, threadIdx.x, fb);
  }
  if (threadIdx.x < 128) {
    int cch = threadIdx.x;
    float s = 0.f, s2 = 0.f;
#pragma unroll
    for (int r = 0; r < NREP; ++r) {
      s  += accIn[r * 256 + cch];
      s2 += accIn[r * 256 + 128 + cch];
    }
    float mean = s * inv_n;
    float var = s2 * inv_n - mean * mean;
    float sc = ldf(bg, (size_t)gOff + cch, fb) * rsqrtf(var + EPSV);
    SC[cch] = sc;
    SH[cch] = ldf(bbeta, (size_t)gOff + cch, fb) - mean * sc;
  }
  __syncthreads();
  float bias2 = ldf(pb2, 0, fb);
  int q = threadIdx.x & 31, g8 = threadIdx.x >> 5;
  int c = q * 4;
  float4 sc = *(const float4*)&SC[c];
  float4 sh = *(const float4*)&SH[c];
  float cs0 = 0, cs1 = 0, cs2 = 0, cs3 = 0;
  for (int node = blockIdx.x * 8 + g8; node < n; node += gridDim.x * 8) {
    uint2 pv = *(const uint2*)(pre + (size_t)node * 128 + c);
    uint2 rv = *(const uint2*)(hbuf + (size_t)node * 128 + c);
    float4 h4;
    h4.x = fmaxf(fmaf(lo2f(pv.x), sc.x, sh.x), 0.f) + lo2f(rv.x);
    h4.y = fmaxf(fmaf(hi2f(pv.x), sc.y, sh.y), 0.f) + hi2f(rv.x);
    h4.z = fmaxf(fmaf(lo2f(pv.y), sc.z, sh.z), 0.f) + lo2f(rv.y);
    h4.w = fmaxf(fmaf(hi2f(pv.y), sc.w, sh.w), 0.f) + hi2f(rv.y);
    cs0 += h4.x; cs1 += h4.y; cs2 += h4.z; cs3 += h4.w;
    float acc = B1v[q];
#pragma unroll
    for (int k4 = 0; k4 < 32; ++k4) {
      float hx = __shfl(h4.x, k4, 32);
      float hy = __shfl(h4.y, k4, 32);
      float hz = __shfl(h4.z, k4, 32);
      float hw = __shfl(h4.w, k4, 32);
      int k = k4 * 4;
      acc = fmaf(hx, W1[k * 32 + q], acc);
      acc = fmaf(hy, W1[(k + 1) * 32 + q], acc);
      acc = fmaf(hz, W1[(k + 2) * 32 + q], acc);
      acc = fmaf(hw, W1[(k + 3) * 32 + q], acc);
    }
    acc = fmaxf(acc, 0.f) * W2v[q];
    for (int off = 16; off; off >>= 1) acc += __shfl_down(acc, off, 32);
    if (q == 0) {
      float v = acc + bias2;
      if (fb) ((bf16*)out)[node] = __float2bfloat16(v);
      else    ((float*)out)[node] = v;
    }
  }
  __shared__ float4 SS[256];
  SS[threadIdx.x] = make_float4(cs0, cs1, cs2, cs3);
  __syncthreads();
  if (threadIdx.x < 32) {
    float4 a = SS[threadIdx.x];
    for (int g2 = 1; g2 < 8; ++g2) {
      float4 u = SS[g2 * 32 + threadIdx.x];
      a.x += u.x; a.y += u.y; a.z += u.z; a.w += u.w;
    }
    float* pr = ppacc + (blockIdx.x & (NREP - 1)) * 128;
    int cc = threadIdx.x * 4;
    atomicAdd(&pr[cc + 0], a.x); atomicAdd(&pr[cc + 1], a.y);
    atomicAdd(&pr[cc + 2], a.z); atomicAdd(&pr[cc + 3], a.w);
  }
  __syncthreads();   // all this block's ppacc adds performed before counter bump
  if (threadIdx.x == 0) {
    int old = atomicAdd(pctr, 1);
    plast = (old == (int)gridDim.x - 1) ? 1 : 0;
  }
  __syncthreads();
  if (plast) {
    __shared__ float gs[128];
    if (threadIdx.x < 128) {
      float t = 0.f;
#pragma unroll
      for (int r = 0; r < NREP; ++r)
        t += atomicAdd(&ppacc[r * 128 + threadIdx.x], 0.f);  // coherent read
      gs[threadIdx.x] = t;
    }
    __syncthreads();
    if (threadIdx.x < 64) {
      int cc = threadIdx.x;
      float acc2 = ldf(vb1, cc, fb);
      for (int k = 0; k < 128; ++k)
        acc2 = fmaf(gs[k] * inv_n, ldf(vW1, (size_t)k * 64 + cc, fb), acc2);
      acc2 = fmaxf(acc2, 0.f);
      float v = acc2 * ldf(vW2, cc, fb);
      for (int off = 32; off; off >>= 1) v += __shfl_down(v, off, 64);
      if (cc == 0) {
        float rr = tanhf(v + ldf(vb2, 0, fb));
        if (fb) ((bf16*)out)[n] = __float2bfloat16(rr);
        else    ((float*)out)[n] = rr;
      }
    }
  }
}

// ---------------- host ----------------

extern "C" void kernel_launch(void* const* d_in, const int* in_sizes, int n_in,
                              void* d_out, int out_size, void* d_ws, size_t ws_size,
                              hipStream_t stream) {
  const void* x       = d_in[0];
  const void* ei      = d_in[1];
  const void* in_W    = d_in[3];
  const void* in_b    = d_in[4];
  const void* in_g    = d_in[5];
  const void* in_beta = d_in[6];
  const void* conv_W  = d_in[7];
  const void* conv_b  = d_in[8];
  const void* bn_g    = d_in[9];
  const void* bn_beta = d_in[10];
  const void* pW1     = d_in[11];
  const void* pb1     = d_in[12];
  const void* pW2     = d_in[13];
  const void* pb2     = d_in[14];
  const void* vW1     = d_in[15];
  const void* vb1     = d_in[16];
  const void* vW2     = d_in[17];
  const void* vb2     = d_in[18];

  const int H = 128;
  int in_dim = in_sizes[3] / H;        // 5
  int n      = in_sizes[0] / in_dim;   // 100000
  int e      = in_sizes[1] / 2;        // 3200000
  int L      = in_sizes[7] / (H * H);  // 6

  const int GS  = 2048;  // gather grid (multiple of 4)
  const int GI  = 512;   // inproj grid (multiple of 8 -> deg XCD affinity preserved)
  const int GP  = 1024;  // policy grid
  const int GF  = 2048;  // deg/fill grid (multiple of 8)

  char* w = (char*)d_ws;
  u16*   u    = (u16*)w;   w += (size_t)n * H * sizeof(u16);
  u16*   pre  = (u16*)w;   w += (size_t)n * H * sizeof(u16);
  u16*   hbuf = (u16*)w;   w += (size_t)n * H * sizeof(u16);
  int*   csr_src  = (int*)w;   w += ((size_t)e + 16) * sizeof(int);
  int*   row_ptr  = (int*)w;   w += (size_t)(n + 1 + 15) / 16 * 16 * sizeof(int);
  int*   degcnt   = (int*)w;   w += (size_t)n * sizeof(int);
  int*   rpw      = (int*)w;   w += (size_t)n * sizeof(int);
  float* dinv     = (float*)w; w += (size_t)n * sizeof(float);
  int*   eflag = (int*)w;   w += 16 * sizeof(int);
  int*   fflag = (int*)w;   w += 16 * sizeof(int);
  int*   bsum  = (int*)w;   w += 256 * sizeof(int);
  int*   wctr  = (int*)w;   w += 32 * sizeof(int);   // 6 layers x 4 slices dynamic counters
  int*   pctr  = (int*)w;   w += 16 * sizeof(int);
  float* buf0  = (float*)w; w += (size_t)NREP * 256 * sizeof(float);
  float* buf1  = (float*)w; w += (size_t)NREP * 256 * sizeof(float);
  float* ppacc = (float*)w; w += (size_t)NREP * 128 * sizeof(float);
  u16*   wf    = (u16*)w;   w += (size_t)L * H * H * sizeof(u16);

  int gN = (n + 255) / 256;
  int nb = (n + 1023) >> 10;
  int nch = (n + CHUNK - 1) / CHUNK;
  int wtotal = L * H * H;
  int GW = (wtotal + 255) / 256;
  float inv_n = 1.0f / (float)n;
  float* bufs[2] = {buf0, buf1};

  setup_kernel<<<gN, 256, 0, stream>>>((const int*)ei, (const unsigned int*)in_g,
                                       eflag, fflag, degcnt, wctr, pctr,
                                       buf0, buf1, ppacc, n);
  pre_merged_kernel<<<GI + GF + GW, 256, 0, stream>>>(
      x, in_W, in_b, ei, conv_W, eflag, fflag, degcnt, pre, buf0, wf,
      n, in_dim, e, wtotal, GI, GF);
  scanA_kernel<<<nb, 256, 0, stream>>>(degcnt, row_ptr, bsum, dinv, n);
  scanB_kernel<<<1, 256, 0, stream>>>(bsum, row_ptr, nb, n, e);
  scanC_kernel<<<gN, 256, 0, stream>>>(row_ptr, bsum, rpw, n);
  fill_kernel<<<GF, 256, 0, stream>>>(ei, eflag, rpw, csr_src, e, n);

  for (int l = 0; l < L; ++l) {
    const void* g    = (l == 0) ? in_g    : bn_g;
    const void* beta = (l == 0) ? in_beta : bn_beta;
    int gOff = (l == 0) ? 0 : (l - 1) * H;
    gemm_bn_kernel<<<2048, 256, 0, stream>>>(pre, hbuf, bufs[l & 1], bufs[(l + 1) & 1],
                                             g, beta, fflag, wf + (size_t)l * H * H,
                                             dinv, u, n, (l > 0) ? 1 : 0, inv_n, gOff);
    gather_stats_kernel<<<GS, 256, 0, stream>>>(row_ptr, csr_src, u, dinv,
                                                conv_b, fflag, pre, bufs[(l + 1) & 1],
                                                wctr + l * 4, n, nch, (size_t)l * H);
  }

  policy_pool_kernel<<<GP, 256, 0, stream>>>(pre, hbuf, bufs[L & 1],
                                             bn_g, bn_beta, (L - 1) * H,
                                             pW1, pb1, pW2, pb2, vW1, vb1, vW2, vb2,
                                             fflag, ppacc, pctr, d_out, n, inv_n);
}